// Round 4
// baseline (405.446 us; speedup 1.0000x reference)
//
#include <hip/hip_runtime.h>

#define DEV __device__ __forceinline__

typedef short short4v __attribute__((ext_vector_type(4)));
typedef short short8v __attribute__((ext_vector_type(8)));
typedef float float4v __attribute__((ext_vector_type(4)));
typedef unsigned short u16;

DEV unsigned short f2bf(float f) {
  unsigned u = __builtin_bit_cast(unsigned, f);
  u += 0x7fffu + ((u >> 16) & 1u);
  return (unsigned short)(u >> 16);
}
DEV float bf2f(unsigned short h) {
  unsigned u = ((unsigned)h) << 16;
  return __builtin_bit_cast(float, u);
}
DEV float4v mfma32(short8v a, short8v b, float4v c) {
  return __builtin_amdgcn_mfma_f32_16x16x32_bf16(a, b, c, 0, 0, 0);
}
DEV float4v mfma16(short4v a, short4v b, float4v c) {
  return __builtin_amdgcn_mfma_f32_16x16x16bf16_1k(a, b, c, 0, 0, 0);
}
DEV void async16(const void* g, void* l) {
  __builtin_amdgcn_global_load_lds(
      (const __attribute__((address_space(1))) unsigned*)g,
      (__attribute__((address_space(3))) unsigned*)l, 16, 0, 0);
}
DEV short4v cvt4(float4v v) {
  short4v r;
  r[0] = (short)f2bf(v[0]); r[1] = (short)f2bf(v[1]);
  r[2] = (short)f2bf(v[2]); r[3] = (short)f2bf(v[3]);
  return r;
}

// ---------------- input conversion f32 -> bf16 ----------------
__global__ __launch_bounds__(256)
void cvt_in(const float* __restrict__ q, const float* __restrict__ kv,
            u16* __restrict__ qb, u16* __restrict__ kvb) {
  const float* src = blockIdx.y ? kv : q;
  u16* dst = blockIdx.y ? kvb : qb;
  size_t i = ((size_t)blockIdx.x * 256 + threadIdx.x) * 8;
  float4v a = *(const float4v*)(src + i);
  float4v b = *(const float4v*)(src + i + 4);
  short8v o;
  o[0] = (short)f2bf(a[0]); o[1] = (short)f2bf(a[1]);
  o[2] = (short)f2bf(a[2]); o[3] = (short)f2bf(a[3]);
  o[4] = (short)f2bf(b[0]); o[5] = (short)f2bf(b[1]);
  o[6] = (short)f2bf(b[2]); o[7] = (short)f2bf(b[3]);
  *(short8v*)(dst + i) = o;
}

// ------------- weight convert + transpose: dst[c*R + r] = src[r*C + c] -------------
__global__ __launch_bounds__(256)
void cvt_w(const float* Wq, const float* Wk, const float* Wv, const float* Wo,
           const float* W1, const float* W2,
           u16* Wqt, u16* Wkt, u16* Wvt, u16* Wot, u16* W1t, u16* W2t) {
  const float* src; u16* dst; int R, C;
  switch (blockIdx.y) {
    case 0: src = Wq; dst = Wqt; R = 256;  C = 256;  break;
    case 1: src = Wk; dst = Wkt; R = 256;  C = 256;  break;
    case 2: src = Wv; dst = Wvt; R = 256;  C = 256;  break;
    case 3: src = Wo; dst = Wot; R = 256;  C = 256;  break;
    case 4: src = W1; dst = W1t; R = 256;  C = 1024; break;
    default: src = W2; dst = W2t; R = 1024; C = 256; break;
  }
  int i = blockIdx.x * 256 + threadIdx.x;
  if (i < R * C) {
    int r = i % R, c = i / R;
    dst[i] = f2bf(src[(size_t)r * C + c]);
  }
}

// ---------------- 128x128-tile GEMM: out = A @ Wt^T + bias (+resid) ----------------
// A: [M][K] bf16, Wt: [N][K] bf16, out: [M][N] bf16. BK=64 (128B LDS rows).
template<bool RESID>
__global__ __launch_bounds__(256, 2)
void gemm128(const u16* __restrict__ A, const u16* __restrict__ Wt,
             const float* __restrict__ bias, const float* __restrict__ resid,
             u16* __restrict__ out, int M, int N, int K) {
  __shared__ alignas(16) char sm[32768];
  char* sa = sm;
  char* sb = sm + 16384;
  const int tid = threadIdx.x;
  const int w = tid >> 6, lane = tid & 63;
  const int ln15 = lane & 15, gq = lane >> 4;
  const int wr = w >> 1, wc = w & 1;
  const int m0 = blockIdx.x * 128, n0 = blockIdx.y * 128;
  const char* Ab = (const char*)A;
  const char* Wb = (const char*)Wt;
  const int Kb = K * 2;  // row bytes

  float4v acc[4][4] = {};
  const int nk = K >> 6;
  for (int kk = 0; kk < nk; ++kk) {
    #pragma unroll
    for (int p = 0; p < 4; ++p) {
      int L = p * 4096 + w * 1024 + lane * 16;
      int row = L >> 7, colb = L & 127;
      int sw = colb ^ ((row & 7) << 4);
      async16(Ab + (size_t)(m0 + row) * Kb + kk * 128 + sw, sa + p * 4096 + w * 1024);
      async16(Wb + (size_t)(n0 + row) * Kb + kk * 128 + sw, sb + p * 4096 + w * 1024);
    }
    __syncthreads();
    #pragma unroll
    for (int ks = 0; ks < 2; ++ks) {
      short8v af[4], bfr[4];
      #pragma unroll
      for (int mf = 0; mf < 4; ++mf) {
        int r = wr * 64 + mf * 16 + ln15;
        af[mf] = *(const short8v*)(sa + r * 128 + ((ks * 64 + gq * 16) ^ ((r & 7) << 4)));
      }
      #pragma unroll
      for (int nf = 0; nf < 4; ++nf) {
        int r = wc * 64 + nf * 16 + ln15;
        bfr[nf] = *(const short8v*)(sb + r * 128 + ((ks * 64 + gq * 16) ^ ((r & 7) << 4)));
      }
      #pragma unroll
      for (int mf = 0; mf < 4; ++mf)
        #pragma unroll
        for (int nf = 0; nf < 4; ++nf)
          acc[mf][nf] = mfma32(af[mf], bfr[nf], acc[mf][nf]);
    }
    __syncthreads();
  }
  #pragma unroll
  for (int nf = 0; nf < 4; ++nf) {
    int col = n0 + wc * 64 + nf * 16 + ln15;
    float bb = bias[col];
    #pragma unroll
    for (int mf = 0; mf < 4; ++mf) {
      int rb = m0 + wr * 64 + mf * 16 + 4 * gq;
      #pragma unroll
      for (int j = 0; j < 4; ++j) {
        size_t idx = (size_t)(rb + j) * N + col;
        float v = acc[mf][nf][j] + bb;
        if (RESID) v += resid[idx];
        out[idx] = f2bf(v);
      }
    }
  }
}

// ---------------- merged K/V projection GEMM ----------------
// A: [M][256] bf16, Wt: stacked [512][256] ([0:256)=Wk^T, [256:512)=Wv^T).
// col<256 -> Kout, else Vout (both [M][256]).
__global__ __launch_bounds__(256, 2)
void gemm_kv(const u16* __restrict__ A, const u16* __restrict__ Wt,
             const float* __restrict__ bk, const float* __restrict__ bv,
             u16* __restrict__ Kout, u16* __restrict__ Vout) {
  __shared__ alignas(16) char sm[32768];
  char* sa = sm;
  char* sb = sm + 16384;
  const int tid = threadIdx.x;
  const int w = tid >> 6, lane = tid & 63;
  const int ln15 = lane & 15, gq = lane >> 4;
  const int wr = w >> 1, wc = w & 1;
  const int m0 = blockIdx.x * 128, n0 = blockIdx.y * 128;
  const char* Ab = (const char*)A;
  const char* Wb = (const char*)Wt;

  float4v acc[4][4] = {};
  for (int kk = 0; kk < 4; ++kk) {
    #pragma unroll
    for (int p = 0; p < 4; ++p) {
      int L = p * 4096 + w * 1024 + lane * 16;
      int row = L >> 7, colb = L & 127;
      int sw = colb ^ ((row & 7) << 4);
      async16(Ab + (size_t)(m0 + row) * 512 + kk * 128 + sw, sa + p * 4096 + w * 1024);
      async16(Wb + (size_t)(n0 + row) * 512 + kk * 128 + sw, sb + p * 4096 + w * 1024);
    }
    __syncthreads();
    #pragma unroll
    for (int ks = 0; ks < 2; ++ks) {
      short8v af[4], bfr[4];
      #pragma unroll
      for (int mf = 0; mf < 4; ++mf) {
        int r = wr * 64 + mf * 16 + ln15;
        af[mf] = *(const short8v*)(sa + r * 128 + ((ks * 64 + gq * 16) ^ ((r & 7) << 4)));
      }
      #pragma unroll
      for (int nf = 0; nf < 4; ++nf) {
        int r = wc * 64 + nf * 16 + ln15;
        bfr[nf] = *(const short8v*)(sb + r * 128 + ((ks * 64 + gq * 16) ^ ((r & 7) << 4)));
      }
      #pragma unroll
      for (int mf = 0; mf < 4; ++mf)
        #pragma unroll
        for (int nf = 0; nf < 4; ++nf)
          acc[mf][nf] = mfma32(af[mf], bfr[nf], acc[mf][nf]);
    }
    __syncthreads();
  }
  #pragma unroll
  for (int nf = 0; nf < 4; ++nf) {
    int col = n0 + wc * 64 + nf * 16 + ln15;  // 0..511
    const bool isK = col < 256;
    const int c2 = isK ? col : col - 256;
    u16* outp = isK ? Kout : Vout;
    float bb = isK ? bk[c2] : bv[c2];
    #pragma unroll
    for (int mf = 0; mf < 4; ++mf) {
      int rb = m0 + wr * 64 + mf * 16 + 4 * gq;
      #pragma unroll
      for (int j = 0; j < 4; ++j)
        outp[(size_t)(rb + j) * 256 + c2] = f2bf(acc[mf][nf][j] + bb);
    }
  }
}

// ---------------- windowed attention, one block per (window, head, q-half) ----------------
// Q,K,V: [65536][256] bf16 (head slice at h*32). ctx out same layout.
__global__ __launch_bounds__(256, 2)
void attn_kernel(const u16* __restrict__ Qg, const u16* __restrict__ Kg,
                 const u16* __restrict__ Vg, u16* __restrict__ ctx) {
  __shared__ alignas(16) char vs[256 * 80];  // V tile, 80B padded rows (conflict-free)
  const int bw = blockIdx.x;
  const int win = bw >> 4, head = (bw >> 1) & 7, qh = bw & 1;
  const int tid = threadIdx.x;
  const int w = tid >> 6, lane = tid & 63;
  const int ln15 = lane & 15, gq = lane >> 4;
  const int tok0 = win << 8;
  const int q0 = qh * 128 + w * 32;

  // stage V [256][32] into padded LDS
  {
    const u16* src = Vg + (size_t)(tok0 + tid) * 256 + head * 32;
    char* dst = vs + tid * 80;
    #pragma unroll
    for (int i = 0; i < 4; ++i)
      *(short8v*)(dst + i * 16) = *(const short8v*)(src + i * 8);
  }

  // Q B-fragments (2 x 16 q-cols), direct from global
  short8v qf[2];
  #pragma unroll
  for (int qi = 0; qi < 2; ++qi)
    qf[qi] = *(const short8v*)(Qg + (size_t)(tok0 + q0 + qi * 16 + ln15) * 256 + head * 32 + gq * 8);

  // S^T = K @ Q^T  (16 key-frags x 2 q-frags), dh=32 -> single MFMA each
  float4v s[16][2];
  #pragma unroll
  for (int kf = 0; kf < 16; ++kf) {
    short8v kfr = *(const short8v*)(Kg + (size_t)(tok0 + kf * 16 + ln15) * 256 + head * 32 + gq * 8);
    float4v z = {0.f, 0.f, 0.f, 0.f};
    s[kf][0] = mfma32(kfr, qf[0], z);
    s[kf][1] = mfma32(kfr, qf[1], z);
  }
  __syncthreads();  // V staged

  // softmax over k (rows of S^T): per-lane 64 vals + 4-lane reduce (xor 16,32)
  const float KSC = (float)(1.4426950408889634 / 5.656854249492381);  // log2e/sqrt(32)
  float rs[2];
  #pragma unroll
  for (int qi = 0; qi < 2; ++qi) {
    float mx = -1e30f;
    #pragma unroll
    for (int kf = 0; kf < 16; ++kf)
      #pragma unroll
      for (int j = 0; j < 4; ++j) mx = fmaxf(mx, s[kf][qi][j]);
    mx = fmaxf(mx, __shfl_xor(mx, 16));
    mx = fmaxf(mx, __shfl_xor(mx, 32));
    float sum = 0.f;
    #pragma unroll
    for (int kf = 0; kf < 16; ++kf)
      #pragma unroll
      for (int j = 0; j < 4; ++j) {
        float p = exp2f((s[kf][qi][j] - mx) * KSC);
        s[kf][qi][j] = p;
        sum += p;
      }
    sum += __shfl_xor(sum, 16);
    sum += __shfl_xor(sum, 32);
    rs[qi] = 1.0f / sum;
  }

  // ctx^T = V^T @ P^T via 16x16x16 (P^T frags feed B-operand lane-for-lane)
  float4v cacc[2][2] = {};  // [df][qi]
  #pragma unroll
  for (int ks = 0; ks < 16; ++ks) {
    short4v pb[2];
    pb[0] = cvt4(s[ks][0]);
    pb[1] = cvt4(s[ks][1]);
    #pragma unroll
    for (int df = 0; df < 2; ++df) {
      const char* vb = vs + (size_t)(16 * ks + 4 * gq) * 80 + (df * 16 + ln15) * 2;
      short4v va;
      va[0] = *(const short*)(vb);
      va[1] = *(const short*)(vb + 80);
      va[2] = *(const short*)(vb + 160);
      va[3] = *(const short*)(vb + 240);
      cacc[df][0] = mfma16(va, pb[0], cacc[df][0]);
      cacc[df][1] = mfma16(va, pb[1], cacc[df][1]);
    }
  }

  // scale by 1/sum and store (d contiguous 4 -> 8B stores)
  #pragma unroll
  for (int qi = 0; qi < 2; ++qi)
    #pragma unroll
    for (int df = 0; df < 2; ++df) {
      short4v o;
      #pragma unroll
      for (int j = 0; j < 4; ++j) o[j] = (short)f2bf(cacc[df][qi][j] * rs[qi]);
      *(short4v*)(ctx + (size_t)(tok0 + q0 + qi * 16 + ln15) * 256 + head * 32 + df * 16 + 4 * gq) = o;
    }
}

// ---------------- row-wise LayerNorm in place (bf16), one wave per row ----------------
__global__ __launch_bounds__(256, 4)
void ln_rows(u16* __restrict__ x, const float* __restrict__ g, const float* __restrict__ b) {
  int row = blockIdx.x * 4 + (threadIdx.x >> 6);
  int lane = threadIdx.x & 63;
  u16* p = x + (size_t)row * 256 + lane * 4;
  short4v v = *(short4v*)p;
  float f[4];
  #pragma unroll
  for (int i = 0; i < 4; ++i) f[i] = bf2f((unsigned short)v[i]);
  float s = f[0] + f[1] + f[2] + f[3];
  float ss = f[0] * f[0] + f[1] * f[1] + f[2] * f[2] + f[3] * f[3];
  #pragma unroll
  for (int m = 1; m <= 32; m <<= 1) {
    s += __shfl_xor(s, m);
    ss += __shfl_xor(ss, m);
  }
  float mu = s * (1.f / 256.f);
  float var = ss * (1.f / 256.f) - mu * mu;
  float rstd = rsqrtf(var + 1e-5f);
  #pragma unroll
  for (int i = 0; i < 4; ++i) {
    int c = lane * 4 + i;
    float o = (f[i] - mu) * rstd * g[c] + b[c];
    v[i] = (short)f2bf(o);
  }
  *(short4v*)p = v;
}

// ---------------- fused FFN v3 + residual + LN2 ----------------
// out = LN2(x + relu(x@W1+b1)@W2 + b2). 512 threads, 128 rows/block; wave owns
// 16 rows; x and h1 in registers (swapped GEMM1 -> mfma16 A-frag). Double-buffered
// W1 (global_load_lds, swizzled) + W2 (reg-staged, 80B-padded rows); b1 in LDS.
__global__ __launch_bounds__(512, 4)
void ffn_v3(const u16* __restrict__ X, const u16* __restrict__ W1t,
            const u16* __restrict__ W2t, const float* __restrict__ b1,
            const float* __restrict__ b2, const float* __restrict__ g2,
            const float* __restrict__ be2, float* __restrict__ out) {
  __shared__ alignas(16) char w1c[2][16384];   // [32 f][512B k], XOR-swizzled
  __shared__ alignas(16) char w2c[2][20480];   // [256 n][80B] (64B data + 16 pad)
  __shared__ alignas(16) float b1s[1024];
  const int tid = threadIdx.x;  // 0..511
  const int w = tid >> 6, lane = tid & 63;
  const int ln15 = lane & 15, gq = lane >> 4;
  const int m0 = blockIdx.x * 128;
  const int xrow = m0 + w * 16 + ln15;

  b1s[tid] = b1[tid];
  b1s[tid + 512] = b1[tid + 512];

  // x rows in registers (B-frags for swapped GEMM1): 8 k-chunks of 32
  short8v xr[8];
  #pragma unroll
  for (int kc = 0; kc < 8; ++kc)
    xr[kc] = *(const short8v*)(X + (size_t)xrow * 256 + kc * 32 + gq * 8);

  float4v ff[16] = {};  // output acc: col = nt*16+ln15, row = w*16 + 4gq + j
  short8v w2r[2];       // W2 chunk staging regs

  const char* W1b = (const char*)W1t;
  const char* W2b = (const char*)W2t;

  // ---- staging helpers (c = chunk index 0..31); 512 threads -> 2 p each ----
  #define STAGE_W1(buf, c)                                                     \
    {                                                                          \
      _Pragma("unroll")                                                        \
      for (int p = 0; p < 2; ++p) {                                            \
        int L = p * 8192 + tid * 16;                                           \
        int r = L >> 9, colb = L & 511;                                        \
        async16(W1b + (size_t)((c) * 32 + r) * 512 + (colb ^ ((r & 7) << 4)),  \
                w1c[buf] + L);                                                 \
      }                                                                        \
    }
  #define LOAD_W2(c)                                                           \
    {                                                                          \
      _Pragma("unroll")                                                        \
      for (int p = 0; p < 2; ++p) {                                            \
        int idx = p * 8192 + tid * 16;                                         \
        int n = idx >> 6, off = idx & 63;                                      \
        w2r[p] = *(const short8v*)(W2b + (size_t)n * 2048 + (c) * 64 + off);   \
      }                                                                        \
    }
  #define WRITE_W2(buf)                                                        \
    {                                                                          \
      _Pragma("unroll")                                                        \
      for (int p = 0; p < 2; ++p) {                                            \
        int idx = p * 8192 + tid * 16;                                         \
        int n = idx >> 6, off = idx & 63;                                      \
        *(short8v*)(w2c[buf] + n * 80 + off) = w2r[p];                         \
      }                                                                        \
    }

  STAGE_W1(0, 0);
  LOAD_W2(0);
  WRITE_W2(0);
  __syncthreads();

  #pragma unroll 2
  for (int c = 0; c < 32; ++c) {
    const int buf = c & 1;
    if (c < 31) {
      STAGE_W1(buf ^ 1, c + 1);
      LOAD_W2(c + 1);
    }

    // GEMM1 (swapped): h1^T[f-tile][xrow] = W1 @ x^T, k = 256
    float4v g1[2] = {};
    #pragma unroll
    for (int kc = 0; kc < 8; ++kc) {
      #pragma unroll
      for (int ft = 0; ft < 2; ++ft) {
        int r = ft * 16 + ln15;
        short8v a = *(const short8v*)(w1c[buf] + r * 512 +
                                      ((kc * 64 + gq * 16) ^ ((r & 7) << 4)));
        g1[ft] = mfma32(a, xr[kc], g1[ft]);
      }
    }
    // bias (via LDS broadcast) + relu + pack:
    // lane holds h1[row=ln15][f = c*32 + ft*16 + 4gq + j]
    short4v pa[2];
    #pragma unroll
    for (int ft = 0; ft < 2; ++ft) {
      float4v bv4 = *(const float4v*)(b1s + c * 32 + ft * 16 + 4 * gq);
      #pragma unroll
      for (int j = 0; j < 4; ++j) {
        float v = g1[ft][j] + bv4[j];
        v = v > 0.f ? v : 0.f;
        pa[ft][j] = (short)f2bf(v);
      }
    }
    // GEMM2: ff[row][n] += h1 @ W2chunk  (mfma16; pa is the A-frag directly)
    #pragma unroll
    for (int nt = 0; nt < 16; ++nt) {
      const char* base = w2c[buf] + (nt * 16 + ln15) * 80 + gq * 8;
      short4v b0 = *(const short4v*)(base);
      short4v b1f = *(const short4v*)(base + 32);
      ff[nt] = mfma16(pa[0], b0, ff[nt]);
      ff[nt] = mfma16(pa[1], b1f, ff[nt]);
    }

    if (c < 31) WRITE_W2(buf ^ 1);
    __syncthreads();
  }

  // ---- epilogue: + b2 + x residual, LN2 per row (16-lane reduce), f32 out ----
  #pragma unroll
  for (int j = 0; j < 4; ++j) {
    int r2 = m0 + w * 16 + 4 * gq + j;
    float sum = 0.f, sq = 0.f;
    #pragma unroll
    for (int nt = 0; nt < 16; ++nt) {
      int col = nt * 16 + ln15;
      float xv = bf2f(X[(size_t)r2 * 256 + col]);
      float v = ff[nt][j] + b2[col] + xv;
      ff[nt][j] = v;
      sum += v;
      sq += v * v;
    }
    #pragma unroll
    for (int m = 1; m <= 8; m <<= 1) {
      sum += __shfl_xor(sum, m);
      sq += __shfl_xor(sq, m);
    }
    float mu = sum * (1.f / 256.f);
    float var = sq * (1.f / 256.f) - mu * mu;
    float rstd = rsqrtf(var + 1e-5f);
    #pragma unroll
    for (int nt = 0; nt < 16; ++nt) {
      int col = nt * 16 + ln15;
      out[(size_t)r2 * 256 + col] = (ff[nt][j] - mu) * rstd * g2[col] + be2[col];
    }
  }
  #undef STAGE_W1
  #undef LOAD_W2
  #undef WRITE_W2
}

extern "C" void kernel_launch(void* const* d_in, const int* in_sizes, int n_in,
                              void* d_out, int out_size, void* d_ws, size_t ws_size,
                              hipStream_t stream) {
  (void)in_sizes; (void)n_in; (void)out_size;
  const float* query = (const float*)d_in[0];
  const float* kv    = (const float*)d_in[1];
  const float* Wqm = (const float*)d_in[2];  const float* bq = (const float*)d_in[3];
  const float* Wkm = (const float*)d_in[4];  const float* bk = (const float*)d_in[5];
  const float* Wvm = (const float*)d_in[6];  const float* bv = (const float*)d_in[7];
  const float* Wom = (const float*)d_in[8];  const float* bo = (const float*)d_in[9];
  const float* ln1g = (const float*)d_in[10]; const float* ln1b = (const float*)d_in[11];
  const float* W1m = (const float*)d_in[12]; const float* b1 = (const float*)d_in[13];
  const float* W2m = (const float*)d_in[14]; const float* b2 = (const float*)d_in[15];
  const float* ln2g = (const float*)d_in[16]; const float* ln2b = (const float*)d_in[17];
  float* out = (float*)d_out;

  char* ws = (char*)d_ws;
  const size_t MB = 1ull << 20;
  if (ws_size < 130 * MB) return;  // avoid OOB if workspace too small

  // lifetime-aliased layout (all bf16):
  u16* qbf  = (u16*)(ws);            // [0,32M)  input q bf16; dead after Q-proj
  u16* kvbf = (u16*)(ws + 32 * MB);  // [32,64M) input kv bf16; dead after V-proj
  u16* Vw   = (u16*)(ws);            // aliases qbf
  u16* ctxw = (u16*)(ws + 32 * MB);  // aliases kvbf
  u16* Qw   = (u16*)(ws + 64 * MB);  // dead after attn
  u16* xw   = (u16*)(ws + 64 * MB);  // aliases Qw
  u16* Kw   = (u16*)(ws + 96 * MB);
  char* wb = ws + 128 * MB;
  u16* Wqt = (u16*)(wb);
  u16* Wkt = (u16*)(wb + 131072);   // Wkt [256][256] and Wvt [256][256] are
  u16* Wvt = (u16*)(wb + 262144);   // contiguous -> stacked [512][256] at Wkt
  u16* Wot = (u16*)(wb + 393216);
  u16* W1t = (u16*)(wb + 524288);
  u16* W2t = (u16*)(wb + 1048576);

  cvt_in<<<dim3(8192, 2), 256, 0, stream>>>(query, kv, qbf, kvbf);
  cvt_w<<<dim3(1024, 6), 256, 0, stream>>>(Wqm, Wkm, Wvm, Wom, W1m, W2m,
                                           Wqt, Wkt, Wvt, Wot, W1t, W2t);
  gemm128<false><<<dim3(512, 2), 256, 0, stream>>>(qbf,  Wqt, bq, nullptr, Qw, 65536, 256, 256);
  gemm_kv<<<dim3(512, 4), 256, 0, stream>>>(kvbf, Wkt, bk, bv, Kw, Vw);
  attn_kernel<<<dim3(4096), 256, 0, stream>>>(Qw, Kw, Vw, ctxw);
  gemm128<true><<<dim3(512, 2), 256, 0, stream>>>(ctxw, Wot, bo, query, xw, 65536, 256, 256);
  ln_rows<<<dim3(16384), 256, 0, stream>>>(xw, ln1g, ln1b);
  ffn_v3<<<dim3(512), 512, 0, stream>>>(xw, W1t, W2t, b1, b2, ln2g, ln2b, out);
}

// Round 6
// 356.489 us; speedup vs baseline: 1.1373x; 1.1373x over previous
//
#include <hip/hip_runtime.h>

#define DEV __device__ __forceinline__

typedef short short4v __attribute__((ext_vector_type(4)));
typedef short short8v __attribute__((ext_vector_type(8)));
typedef float float4v __attribute__((ext_vector_type(4)));
typedef unsigned short u16;

DEV unsigned short f2bf(float f) {
  unsigned u = __builtin_bit_cast(unsigned, f);
  u += 0x7fffu + ((u >> 16) & 1u);
  return (unsigned short)(u >> 16);
}
DEV float bf2f(unsigned short h) {
  unsigned u = ((unsigned)h) << 16;
  return __builtin_bit_cast(float, u);
}
DEV float4v mfma32(short8v a, short8v b, float4v c) {
  return __builtin_amdgcn_mfma_f32_16x16x32_bf16(a, b, c, 0, 0, 0);
}
DEV float4v mfma16(short4v a, short4v b, float4v c) {
  return __builtin_amdgcn_mfma_f32_16x16x16bf16_1k(a, b, c, 0, 0, 0);
}
DEV void async16(const void* g, void* l) {
  __builtin_amdgcn_global_load_lds(
      (const __attribute__((address_space(1))) unsigned*)g,
      (__attribute__((address_space(3))) unsigned*)l, 16, 0, 0);
}
DEV short4v cvt4(float4v v) {
  short4v r;
  r[0] = (short)f2bf(v[0]); r[1] = (short)f2bf(v[1]);
  r[2] = (short)f2bf(v[2]); r[3] = (short)f2bf(v[3]);
  return r;
}

// ---------------- input conversion f32 -> bf16 ----------------
__global__ __launch_bounds__(256)
void cvt_in(const float* __restrict__ q, const float* __restrict__ kv,
            u16* __restrict__ qb, u16* __restrict__ kvb) {
  const float* src = blockIdx.y ? kv : q;
  u16* dst = blockIdx.y ? kvb : qb;
  size_t i = ((size_t)blockIdx.x * 256 + threadIdx.x) * 8;
  float4v a = *(const float4v*)(src + i);
  float4v b = *(const float4v*)(src + i + 4);
  short8v o;
  o[0] = (short)f2bf(a[0]); o[1] = (short)f2bf(a[1]);
  o[2] = (short)f2bf(a[2]); o[3] = (short)f2bf(a[3]);
  o[4] = (short)f2bf(b[0]); o[5] = (short)f2bf(b[1]);
  o[6] = (short)f2bf(b[2]); o[7] = (short)f2bf(b[3]);
  *(short8v*)(dst + i) = o;
}

// ------------- weight convert + transpose: dst[c*R + r] = src[r*C + c] -------------
__global__ __launch_bounds__(256)
void cvt_w(const float* Wq, const float* Wk, const float* Wv, const float* Wo,
           const float* W1, const float* W2,
           u16* Wqt, u16* Wkt, u16* Wvt, u16* Wot, u16* W1t, u16* W2t) {
  const float* src; u16* dst; int R, C;
  switch (blockIdx.y) {
    case 0: src = Wq; dst = Wqt; R = 256;  C = 256;  break;
    case 1: src = Wk; dst = Wkt; R = 256;  C = 256;  break;
    case 2: src = Wv; dst = Wvt; R = 256;  C = 256;  break;
    case 3: src = Wo; dst = Wot; R = 256;  C = 256;  break;
    case 4: src = W1; dst = W1t; R = 256;  C = 1024; break;
    default: src = W2; dst = W2t; R = 1024; C = 256; break;
  }
  int i = blockIdx.x * 256 + threadIdx.x;
  if (i < R * C) {
    int r = i % R, c = i / R;
    dst[i] = f2bf(src[(size_t)r * C + c]);
  }
}

// ---------------- 128x128-tile GEMM: out = A @ Wt^T + bias (+resid) ----------------
// A: [M][K] bf16, Wt: [N][K] bf16, out: [M][N] bf16. BK=64 (128B LDS rows).
template<bool RESID>
__global__ __launch_bounds__(256, 2)
void gemm128(const u16* __restrict__ A, const u16* __restrict__ Wt,
             const float* __restrict__ bias, const float* __restrict__ resid,
             u16* __restrict__ out, int M, int N, int K) {
  __shared__ alignas(16) char sm[32768];
  char* sa = sm;
  char* sb = sm + 16384;
  const int tid = threadIdx.x;
  const int w = tid >> 6, lane = tid & 63;
  const int ln15 = lane & 15, gq = lane >> 4;
  const int wr = w >> 1, wc = w & 1;
  const int m0 = blockIdx.x * 128, n0 = blockIdx.y * 128;
  const char* Ab = (const char*)A;
  const char* Wb = (const char*)Wt;
  const int Kb = K * 2;  // row bytes

  float4v acc[4][4] = {};
  const int nk = K >> 6;
  for (int kk = 0; kk < nk; ++kk) {
    #pragma unroll
    for (int p = 0; p < 4; ++p) {
      int L = p * 4096 + w * 1024 + lane * 16;
      int row = L >> 7, colb = L & 127;
      int sw = colb ^ ((row & 7) << 4);
      async16(Ab + (size_t)(m0 + row) * Kb + kk * 128 + sw, sa + p * 4096 + w * 1024);
      async16(Wb + (size_t)(n0 + row) * Kb + kk * 128 + sw, sb + p * 4096 + w * 1024);
    }
    __syncthreads();
    #pragma unroll
    for (int ks = 0; ks < 2; ++ks) {
      short8v af[4], bfr[4];
      #pragma unroll
      for (int mf = 0; mf < 4; ++mf) {
        int r = wr * 64 + mf * 16 + ln15;
        af[mf] = *(const short8v*)(sa + r * 128 + ((ks * 64 + gq * 16) ^ ((r & 7) << 4)));
      }
      #pragma unroll
      for (int nf = 0; nf < 4; ++nf) {
        int r = wc * 64 + nf * 16 + ln15;
        bfr[nf] = *(const short8v*)(sb + r * 128 + ((ks * 64 + gq * 16) ^ ((r & 7) << 4)));
      }
      #pragma unroll
      for (int mf = 0; mf < 4; ++mf)
        #pragma unroll
        for (int nf = 0; nf < 4; ++nf)
          acc[mf][nf] = mfma32(af[mf], bfr[nf], acc[mf][nf]);
    }
    __syncthreads();
  }
  #pragma unroll
  for (int nf = 0; nf < 4; ++nf) {
    int col = n0 + wc * 64 + nf * 16 + ln15;
    float bb = bias[col];
    #pragma unroll
    for (int mf = 0; mf < 4; ++mf) {
      int rb = m0 + wr * 64 + mf * 16 + 4 * gq;
      #pragma unroll
      for (int j = 0; j < 4; ++j) {
        size_t idx = (size_t)(rb + j) * N + col;
        float v = acc[mf][nf][j] + bb;
        if (RESID) v += resid[idx];
        out[idx] = f2bf(v);
      }
    }
  }
}

// ---------------- merged K/V projection GEMM ----------------
// A: [M][256] bf16, Wt: stacked [512][256] ([0:256)=Wk^T, [256:512)=Wv^T).
// col<256 -> Kout, else Vout (both [M][256]).
__global__ __launch_bounds__(256, 2)
void gemm_kv(const u16* __restrict__ A, const u16* __restrict__ Wt,
             const float* __restrict__ bk, const float* __restrict__ bv,
             u16* __restrict__ Kout, u16* __restrict__ Vout) {
  __shared__ alignas(16) char sm[32768];
  char* sa = sm;
  char* sb = sm + 16384;
  const int tid = threadIdx.x;
  const int w = tid >> 6, lane = tid & 63;
  const int ln15 = lane & 15, gq = lane >> 4;
  const int wr = w >> 1, wc = w & 1;
  const int m0 = blockIdx.x * 128, n0 = blockIdx.y * 128;
  const char* Ab = (const char*)A;
  const char* Wb = (const char*)Wt;

  float4v acc[4][4] = {};
  for (int kk = 0; kk < 4; ++kk) {
    #pragma unroll
    for (int p = 0; p < 4; ++p) {
      int L = p * 4096 + w * 1024 + lane * 16;
      int row = L >> 7, colb = L & 127;
      int sw = colb ^ ((row & 7) << 4);
      async16(Ab + (size_t)(m0 + row) * 512 + kk * 128 + sw, sa + p * 4096 + w * 1024);
      async16(Wb + (size_t)(n0 + row) * 512 + kk * 128 + sw, sb + p * 4096 + w * 1024);
    }
    __syncthreads();
    #pragma unroll
    for (int ks = 0; ks < 2; ++ks) {
      short8v af[4], bfr[4];
      #pragma unroll
      for (int mf = 0; mf < 4; ++mf) {
        int r = wr * 64 + mf * 16 + ln15;
        af[mf] = *(const short8v*)(sa + r * 128 + ((ks * 64 + gq * 16) ^ ((r & 7) << 4)));
      }
      #pragma unroll
      for (int nf = 0; nf < 4; ++nf) {
        int r = wc * 64 + nf * 16 + ln15;
        bfr[nf] = *(const short8v*)(sb + r * 128 + ((ks * 64 + gq * 16) ^ ((r & 7) << 4)));
      }
      #pragma unroll
      for (int mf = 0; mf < 4; ++mf)
        #pragma unroll
        for (int nf = 0; nf < 4; ++nf)
          acc[mf][nf] = mfma32(af[mf], bfr[nf], acc[mf][nf]);
    }
    __syncthreads();
  }
  #pragma unroll
  for (int nf = 0; nf < 4; ++nf) {
    int col = n0 + wc * 64 + nf * 16 + ln15;  // 0..511
    const bool isK = col < 256;
    const int c2 = isK ? col : col - 256;
    u16* outp = isK ? Kout : Vout;
    float bb = isK ? bk[c2] : bv[c2];
    #pragma unroll
    for (int mf = 0; mf < 4; ++mf) {
      int rb = m0 + wr * 64 + mf * 16 + 4 * gq;
      #pragma unroll
      for (int j = 0; j < 4; ++j)
        outp[(size_t)(rb + j) * 256 + c2] = f2bf(acc[mf][nf][j] + bb);
    }
  }
}

// ---------------- windowed attention, one block per (window, head, q-half) ----------------
// Q,K,V: [65536][256] bf16 (head slice at h*32). ctx out same layout.
__global__ __launch_bounds__(256, 2)
void attn_kernel(const u16* __restrict__ Qg, const u16* __restrict__ Kg,
                 const u16* __restrict__ Vg, u16* __restrict__ ctx) {
  __shared__ alignas(16) char vs[256 * 80];  // V tile, 80B padded rows (conflict-free)
  const int bw = blockIdx.x;
  const int win = bw >> 4, head = (bw >> 1) & 7, qh = bw & 1;
  const int tid = threadIdx.x;
  const int w = tid >> 6, lane = tid & 63;
  const int ln15 = lane & 15, gq = lane >> 4;
  const int tok0 = win << 8;
  const int q0 = qh * 128 + w * 32;

  // stage V [256][32] into padded LDS
  {
    const u16* src = Vg + (size_t)(tok0 + tid) * 256 + head * 32;
    char* dst = vs + tid * 80;
    #pragma unroll
    for (int i = 0; i < 4; ++i)
      *(short8v*)(dst + i * 16) = *(const short8v*)(src + i * 8);
  }

  // Q B-fragments (2 x 16 q-cols), direct from global
  short8v qf[2];
  #pragma unroll
  for (int qi = 0; qi < 2; ++qi)
    qf[qi] = *(const short8v*)(Qg + (size_t)(tok0 + q0 + qi * 16 + ln15) * 256 + head * 32 + gq * 8);

  // S^T = K @ Q^T  (16 key-frags x 2 q-frags), dh=32 -> single MFMA each
  float4v s[16][2];
  #pragma unroll
  for (int kf = 0; kf < 16; ++kf) {
    short8v kfr = *(const short8v*)(Kg + (size_t)(tok0 + kf * 16 + ln15) * 256 + head * 32 + gq * 8);
    float4v z = {0.f, 0.f, 0.f, 0.f};
    s[kf][0] = mfma32(kfr, qf[0], z);
    s[kf][1] = mfma32(kfr, qf[1], z);
  }
  __syncthreads();  // V staged

  // softmax over k (rows of S^T): per-lane 64 vals + 4-lane reduce (xor 16,32)
  const float KSC = (float)(1.4426950408889634 / 5.656854249492381);  // log2e/sqrt(32)
  float rs[2];
  #pragma unroll
  for (int qi = 0; qi < 2; ++qi) {
    float mx = -1e30f;
    #pragma unroll
    for (int kf = 0; kf < 16; ++kf)
      #pragma unroll
      for (int j = 0; j < 4; ++j) mx = fmaxf(mx, s[kf][qi][j]);
    mx = fmaxf(mx, __shfl_xor(mx, 16));
    mx = fmaxf(mx, __shfl_xor(mx, 32));
    float sum = 0.f;
    #pragma unroll
    for (int kf = 0; kf < 16; ++kf)
      #pragma unroll
      for (int j = 0; j < 4; ++j) {
        float p = exp2f((s[kf][qi][j] - mx) * KSC);
        s[kf][qi][j] = p;
        sum += p;
      }
    sum += __shfl_xor(sum, 16);
    sum += __shfl_xor(sum, 32);
    rs[qi] = 1.0f / sum;
  }

  // ctx^T = V^T @ P^T via 16x16x16 (P^T frags feed B-operand lane-for-lane)
  float4v cacc[2][2] = {};  // [df][qi]
  #pragma unroll
  for (int ks = 0; ks < 16; ++ks) {
    short4v pb[2];
    pb[0] = cvt4(s[ks][0]);
    pb[1] = cvt4(s[ks][1]);
    #pragma unroll
    for (int df = 0; df < 2; ++df) {
      const char* vb = vs + (size_t)(16 * ks + 4 * gq) * 80 + (df * 16 + ln15) * 2;
      short4v va;
      va[0] = *(const short*)(vb);
      va[1] = *(const short*)(vb + 80);
      va[2] = *(const short*)(vb + 160);
      va[3] = *(const short*)(vb + 240);
      cacc[df][0] = mfma16(va, pb[0], cacc[df][0]);
      cacc[df][1] = mfma16(va, pb[1], cacc[df][1]);
    }
  }

  // scale by 1/sum and store (d contiguous 4 -> 8B stores)
  #pragma unroll
  for (int qi = 0; qi < 2; ++qi)
    #pragma unroll
    for (int df = 0; df < 2; ++df) {
      short4v o;
      #pragma unroll
      for (int j = 0; j < 4; ++j) o[j] = (short)f2bf(cacc[df][qi][j] * rs[qi]);
      *(short4v*)(ctx + (size_t)(tok0 + q0 + qi * 16 + ln15) * 256 + head * 32 + df * 16 + 4 * gq) = o;
    }
}

// ---------------- row-wise LayerNorm in place (bf16), one wave per row ----------------
__global__ __launch_bounds__(256, 4)
void ln_rows(u16* __restrict__ x, const float* __restrict__ g, const float* __restrict__ b) {
  int row = blockIdx.x * 4 + (threadIdx.x >> 6);
  int lane = threadIdx.x & 63;
  u16* p = x + (size_t)row * 256 + lane * 4;
  short4v v = *(short4v*)p;
  float f[4];
  #pragma unroll
  for (int i = 0; i < 4; ++i) f[i] = bf2f((unsigned short)v[i]);
  float s = f[0] + f[1] + f[2] + f[3];
  float ss = f[0] * f[0] + f[1] * f[1] + f[2] * f[2] + f[3] * f[3];
  #pragma unroll
  for (int m = 1; m <= 32; m <<= 1) {
    s += __shfl_xor(s, m);
    ss += __shfl_xor(ss, m);
  }
  float mu = s * (1.f / 256.f);
  float var = ss * (1.f / 256.f) - mu * mu;
  float rstd = rsqrtf(var + 1e-5f);
  #pragma unroll
  for (int i = 0; i < 4; ++i) {
    int c = lane * 4 + i;
    float o = (f[i] - mu) * rstd * g[c] + b[c];
    v[i] = (short)f2bf(o);
  }
  *(short4v*)p = v;
}

// ---------------- fused FFN v5 + residual + LN2 ----------------
// out = LN2(x + relu(x@W1+b1)@W2 + b2). 512 threads, 256 rows/block; wave owns
// 32 rows (2 col-tiles ct of swapped GEMM1); x and h1 in registers; GEMM2 via
// proven mfma16 path (unpermuted W2t, reg-staged 80B-padded LDS rows).
// Double-buffered, T14 load-early/write-late, 1 barrier/chunk.
__global__ __launch_bounds__(512, 2)
void ffn_v5(const u16* __restrict__ X, const u16* __restrict__ W1t,
            const u16* __restrict__ W2t, const float* __restrict__ b1,
            const float* __restrict__ b2, const float* __restrict__ g2,
            const float* __restrict__ be2, float* __restrict__ out) {
  __shared__ alignas(16) char w1c[2][16384];   // [32 f][512B k], XOR-swizzled
  __shared__ alignas(16) char w2c[2][20480];   // [256 n][80B] (64B data + 16 pad)
  __shared__ alignas(16) float b1s[1024];
  const int tid = threadIdx.x;  // 0..511
  const int w = tid >> 6, lane = tid & 63;
  const int ln15 = lane & 15, gq = lane >> 4;
  const int m0 = blockIdx.x * 256;
  const int wrow0 = m0 + w * 32;

  b1s[tid] = b1[tid];
  b1s[tid + 512] = b1[tid + 512];

  // x rows in registers (B-frags for swapped GEMM1): 2 col-tiles x 8 k-chunks
  short8v xr[2][8];
  #pragma unroll
  for (int ct = 0; ct < 2; ++ct)
    #pragma unroll
    for (int kc = 0; kc < 8; ++kc)
      xr[ct][kc] = *(const short8v*)(X + (size_t)(wrow0 + ct * 16 + ln15) * 256 + kc * 32 + gq * 8);

  float4v ff[2][16] = {};  // [ct][nt]: col = nt*16+ln15, row = wrow0+ct*16+4gq+j
  short8v w2r[2];          // W2 chunk staging regs

  const char* W1b = (const char*)W1t;
  const char* W2b = (const char*)W2t;

  // ---- staging helpers (c = chunk index 0..31); 512 threads -> 2 x 16B each ----
  #define STAGE_W1(buf, c)                                                     \
    {                                                                          \
      _Pragma("unroll")                                                        \
      for (int p = 0; p < 2; ++p) {                                            \
        int L = p * 8192 + tid * 16;                                           \
        int r = L >> 9, colb = L & 511;                                        \
        async16(W1b + (size_t)((c) * 32 + r) * 512 + (colb ^ ((r & 7) << 4)),  \
                w1c[buf] + L);                                                 \
      }                                                                        \
    }
  #define LOAD_W2(c)                                                           \
    {                                                                          \
      _Pragma("unroll")                                                        \
      for (int p = 0; p < 2; ++p) {                                            \
        int idx = p * 8192 + tid * 16;                                         \
        int n = idx >> 6, off = idx & 63;                                      \
        w2r[p] = *(const short8v*)(W2b + (size_t)n * 2048 + (c) * 64 + off);   \
      }                                                                        \
    }
  #define WRITE_W2(buf)                                                        \
    {                                                                          \
      _Pragma("unroll")                                                        \
      for (int p = 0; p < 2; ++p) {                                            \
        int idx = p * 8192 + tid * 16;                                         \
        int n = idx >> 6, off = idx & 63;                                      \
        *(short8v*)(w2c[buf] + n * 80 + off) = w2r[p];                         \
      }                                                                        \
    }

  STAGE_W1(0, 0);
  LOAD_W2(0);
  WRITE_W2(0);
  __syncthreads();

  #pragma unroll 2
  for (int c = 0; c < 32; ++c) {
    const int buf = c & 1;
    if (c < 31) {
      STAGE_W1(buf ^ 1, c + 1);
      LOAD_W2(c + 1);
    }

    // GEMM1 (swapped): h1^T[f-tile][xrow] = W1chunk @ x^T, k = 256
    float4v g1[2][2] = {};  // [ct][ft]
    #pragma unroll
    for (int kc = 0; kc < 8; ++kc) {
      #pragma unroll
      for (int ft = 0; ft < 2; ++ft) {
        int r = ft * 16 + ln15;
        short8v a = *(const short8v*)(w1c[buf] + r * 512 +
                                      ((kc * 64 + gq * 16) ^ ((r & 7) << 4)));
        g1[0][ft] = mfma32(a, xr[0][kc], g1[0][ft]);
        g1[1][ft] = mfma32(a, xr[1][kc], g1[1][ft]);
      }
    }
    // bias + relu + pack: lane holds h1[row=ln15][f = c*32 + ft*16 + 4gq + j]
    short4v pa[2][2];  // [ct][ft]
    #pragma unroll
    for (int ft = 0; ft < 2; ++ft) {
      float4v bv4 = *(const float4v*)(b1s + c * 32 + ft * 16 + 4 * gq);
      #pragma unroll
      for (int ct = 0; ct < 2; ++ct)
        #pragma unroll
        for (int j = 0; j < 4; ++j) {
          float v = g1[ct][ft][j] + bv4[j];
          v = v > 0.f ? v : 0.f;
          pa[ct][ft][j] = (short)f2bf(v);
        }
    }
    // GEMM2: ff[row][n] += h1 @ W2chunk  (mfma16; pa is the A-frag directly)
    #pragma unroll
    for (int nt = 0; nt < 16; ++nt) {
      const char* base = w2c[buf] + (nt * 16 + ln15) * 80 + gq * 8;
      short4v b0 = *(const short4v*)(base);
      short4v b1f = *(const short4v*)(base + 32);
      ff[0][nt] = mfma16(pa[0][0], b0, ff[0][nt]);
      ff[0][nt] = mfma16(pa[0][1], b1f, ff[0][nt]);
      ff[1][nt] = mfma16(pa[1][0], b0, ff[1][nt]);
      ff[1][nt] = mfma16(pa[1][1], b1f, ff[1][nt]);
    }

    if (c < 31) WRITE_W2(buf ^ 1);
    __syncthreads();
  }

  // ---- epilogue: + b2 + x residual, LN2 per row (16-lane reduce), f32 out ----
  #pragma unroll
  for (int ct = 0; ct < 2; ++ct)
    #pragma unroll
    for (int j = 0; j < 4; ++j) {
      int r2 = wrow0 + ct * 16 + 4 * gq + j;
      float sum = 0.f, sq = 0.f;
      float vv[16];
      #pragma unroll
      for (int nt = 0; nt < 16; ++nt) {
        int col = nt * 16 + ln15;
        float xv = bf2f(X[(size_t)r2 * 256 + col]);
        float v = ff[ct][nt][j] + b2[col] + xv;
        vv[nt] = v;
        sum += v;
        sq += v * v;
      }
      #pragma unroll
      for (int m = 1; m <= 8; m <<= 1) {
        sum += __shfl_xor(sum, m);
        sq += __shfl_xor(sq, m);
      }
      float mu = sum * (1.f / 256.f);
      float var = sq * (1.f / 256.f) - mu * mu;
      float rstd = rsqrtf(var + 1e-5f);
      #pragma unroll
      for (int nt = 0; nt < 16; ++nt) {
        int col = nt * 16 + ln15;
        out[(size_t)r2 * 256 + col] = (vv[nt] - mu) * rstd * g2[col] + be2[col];
      }
    }
  #undef STAGE_W1
  #undef LOAD_W2
  #undef WRITE_W2
}

extern "C" void kernel_launch(void* const* d_in, const int* in_sizes, int n_in,
                              void* d_out, int out_size, void* d_ws, size_t ws_size,
                              hipStream_t stream) {
  (void)in_sizes; (void)n_in; (void)out_size;
  const float* query = (const float*)d_in[0];
  const float* kv    = (const float*)d_in[1];
  const float* Wqm = (const float*)d_in[2];  const float* bq = (const float*)d_in[3];
  const float* Wkm = (const float*)d_in[4];  const float* bk = (const float*)d_in[5];
  const float* Wvm = (const float*)d_in[6];  const float* bv = (const float*)d_in[7];
  const float* Wom = (const float*)d_in[8];  const float* bo = (const float*)d_in[9];
  const float* ln1g = (const float*)d_in[10]; const float* ln1b = (const float*)d_in[11];
  const float* W1m = (const float*)d_in[12]; const float* b1 = (const float*)d_in[13];
  const float* W2m = (const float*)d_in[14]; const float* b2 = (const float*)d_in[15];
  const float* ln2g = (const float*)d_in[16]; const float* ln2b = (const float*)d_in[17];
  float* out = (float*)d_out;

  char* ws = (char*)d_ws;
  const size_t MB = 1ull << 20;
  if (ws_size < 130 * MB) return;  // avoid OOB if workspace too small

  // lifetime-aliased layout (all bf16):
  u16* qbf  = (u16*)(ws);            // [0,32M)  input q bf16; dead after Q-proj
  u16* kvbf = (u16*)(ws + 32 * MB);  // [32,64M) input kv bf16; dead after V-proj
  u16* Vw   = (u16*)(ws);            // aliases qbf
  u16* ctxw = (u16*)(ws + 32 * MB);  // aliases kvbf
  u16* Qw   = (u16*)(ws + 64 * MB);  // dead after attn
  u16* xw   = (u16*)(ws + 64 * MB);  // aliases Qw
  u16* Kw   = (u16*)(ws + 96 * MB);
  char* wb = ws + 128 * MB;
  u16* Wqt = (u16*)(wb);
  u16* Wkt = (u16*)(wb + 131072);   // Wkt [256][256] and Wvt [256][256] are
  u16* Wvt = (u16*)(wb + 262144);   // contiguous -> stacked [512][256] at Wkt
  u16* Wot = (u16*)(wb + 393216);
  u16* W1t = (u16*)(wb + 524288);
  u16* W2t = (u16*)(wb + 1048576);

  cvt_in<<<dim3(8192, 2), 256, 0, stream>>>(query, kv, qbf, kvbf);
  cvt_w<<<dim3(1024, 6), 256, 0, stream>>>(Wqm, Wkm, Wvm, Wom, W1m, W2m,
                                           Wqt, Wkt, Wvt, Wot, W1t, W2t);
  gemm128<false><<<dim3(512, 2), 256, 0, stream>>>(qbf,  Wqt, bq, nullptr, Qw, 65536, 256, 256);
  gemm_kv<<<dim3(512, 4), 256, 0, stream>>>(kvbf, Wkt, bk, bv, Kw, Vw);
  attn_kernel<<<dim3(4096), 256, 0, stream>>>(Qw, Kw, Vw, ctxw);
  gemm128<true><<<dim3(512, 2), 256, 0, stream>>>(ctxw, Wot, bo, query, xw, 65536, 256, 256);
  ln_rows<<<dim3(16384), 256, 0, stream>>>(xw, ln1g, ln1b);
  ffn_v5<<<dim3(256), 512, 0, stream>>>(xw, W1t, W2t, b1, b2, ln2g, ln2b, out);
}

// Round 7
// 346.307 us; speedup vs baseline: 1.1708x; 1.0294x over previous
//
#include <hip/hip_runtime.h>

#define DEV __device__ __forceinline__

typedef short short4v __attribute__((ext_vector_type(4)));
typedef short short8v __attribute__((ext_vector_type(8)));
typedef float float4v __attribute__((ext_vector_type(4)));
typedef unsigned short u16;

DEV unsigned short f2bf(float f) {
  unsigned u = __builtin_bit_cast(unsigned, f);
  u += 0x7fffu + ((u >> 16) & 1u);
  return (unsigned short)(u >> 16);
}
DEV float bf2f(unsigned short h) {
  unsigned u = ((unsigned)h) << 16;
  return __builtin_bit_cast(float, u);
}
DEV float4v mfma32(short8v a, short8v b, float4v c) {
  return __builtin_amdgcn_mfma_f32_16x16x32_bf16(a, b, c, 0, 0, 0);
}
DEV float4v mfma16(short4v a, short4v b, float4v c) {
  return __builtin_amdgcn_mfma_f32_16x16x16bf16_1k(a, b, c, 0, 0, 0);
}
DEV void async16(const void* g, void* l) {
  __builtin_amdgcn_global_load_lds(
      (const __attribute__((address_space(1))) unsigned*)g,
      (__attribute__((address_space(3))) unsigned*)l, 16, 0, 0);
}
DEV short4v cvt4(float4v v) {
  short4v r;
  r[0] = (short)f2bf(v[0]); r[1] = (short)f2bf(v[1]);
  r[2] = (short)f2bf(v[2]); r[3] = (short)f2bf(v[3]);
  return r;
}

// ---------------- input conversion f32 -> bf16 ----------------
__global__ __launch_bounds__(256)
void cvt_in(const float* __restrict__ q, const float* __restrict__ kv,
            u16* __restrict__ qb, u16* __restrict__ kvb) {
  const float* src = blockIdx.y ? kv : q;
  u16* dst = blockIdx.y ? kvb : qb;
  size_t i = ((size_t)blockIdx.x * 256 + threadIdx.x) * 8;
  float4v a = *(const float4v*)(src + i);
  float4v b = *(const float4v*)(src + i + 4);
  short8v o;
  o[0] = (short)f2bf(a[0]); o[1] = (short)f2bf(a[1]);
  o[2] = (short)f2bf(a[2]); o[3] = (short)f2bf(a[3]);
  o[4] = (short)f2bf(b[0]); o[5] = (short)f2bf(b[1]);
  o[6] = (short)f2bf(b[2]); o[7] = (short)f2bf(b[3]);
  *(short8v*)(dst + i) = o;
}

// ------------- weight convert + transpose (LDS-tiled, coalesced) -------------
// dst[c][r] = src[r][c], 64x64 tiles via padded LDS. For W2 (blockIdx.y==5) the
// dst f-positions are permuted within each 32-block: f'(p) = 16*((p>>2)&1) +
// 4*(p>>3) + (p&3), so ffn's packed GEMM1 output is a valid mfma32 A-operand.
__global__ __launch_bounds__(256)
void cvt_wT(const float* Wq, const float* Wk, const float* Wv, const float* Wo,
            const float* W1, const float* W2,
            u16* Wqt, u16* Wkt, u16* Wvt, u16* Wot, u16* W1t, u16* W2t) {
  __shared__ float ld[64 * 69];
  const float* src; u16* dst; int R, C; bool permk = false;
  switch (blockIdx.y) {
    case 0: src = Wq; dst = Wqt; R = 256;  C = 256;  break;
    case 1: src = Wk; dst = Wkt; R = 256;  C = 256;  break;
    case 2: src = Wv; dst = Wvt; R = 256;  C = 256;  break;
    case 3: src = Wo; dst = Wot; R = 256;  C = 256;  break;
    case 4: src = W1; dst = W1t; R = 256;  C = 1024; break;
    default: src = W2; dst = W2t; R = 1024; C = 256; permk = true; break;
  }
  const int ntile = (R >> 6) * (C >> 6);
  if ((int)blockIdx.x >= ntile) return;
  const int tf = blockIdx.x % (R >> 6);
  const int tn = blockIdx.x / (R >> 6);
  const int r0 = tf << 6, c0 = tn << 6;
  const int tid = threadIdx.x;
  // load 64x64 f32 tile coalesced (4 passes x 16 rows x 16 float4)
  {
    int lr = tid >> 4, lc = (tid & 15) << 2;
    #pragma unroll
    for (int ps = 0; ps < 4; ++ps) {
      int r = ps * 16 + lr;
      float4v v = *(const float4v*)(src + (size_t)(r0 + r) * C + c0 + lc);
      #pragma unroll
      for (int e = 0; e < 4; ++e) ld[r * 69 + lc + e] = v[e];
    }
  }
  __syncthreads();
  // write transposed bf16 rows (2 passes x 32 rows x 8 bf16 per thread)
  {
    int p8 = (tid & 7) << 3;
    #pragma unroll
    for (int ps = 0; ps < 2; ++ps) {
      int n = ps * 32 + (tid >> 3);
      short8v o;
      #pragma unroll
      for (int e = 0; e < 8; ++e) {
        int p = p8 + e;
        int fl = p;
        if (permk) {
          int m = p & 31;
          fl = (p & 32) + 16 * ((m >> 2) & 1) + 4 * (m >> 3) + (m & 3);
        }
        o[e] = (short)f2bf(ld[fl * 69 + n]);
      }
      *(short8v*)(dst + (size_t)(c0 + n) * R + r0 + p8) = o;
    }
  }
}

// ---------------- 128x128-tile GEMM: out = A @ Wt^T + bias (+resid) ----------------
// A: [M][K] bf16, Wt: [N][K] bf16, out: [M][N] bf16. BK=64 (128B LDS rows).
template<bool RESID>
__global__ __launch_bounds__(256, 2)
void gemm128(const u16* __restrict__ A, const u16* __restrict__ Wt,
             const float* __restrict__ bias, const float* __restrict__ resid,
             u16* __restrict__ out, int M, int N, int K) {
  __shared__ alignas(16) char sm[32768];
  char* sa = sm;
  char* sb = sm + 16384;
  const int tid = threadIdx.x;
  const int w = tid >> 6, lane = tid & 63;
  const int ln15 = lane & 15, gq = lane >> 4;
  const int wr = w >> 1, wc = w & 1;
  const int m0 = blockIdx.x * 128, n0 = blockIdx.y * 128;
  const char* Ab = (const char*)A;
  const char* Wb = (const char*)Wt;
  const int Kb = K * 2;  // row bytes

  float4v acc[4][4] = {};
  const int nk = K >> 6;
  for (int kk = 0; kk < nk; ++kk) {
    #pragma unroll
    for (int p = 0; p < 4; ++p) {
      int L = p * 4096 + w * 1024 + lane * 16;
      int row = L >> 7, colb = L & 127;
      int sw = colb ^ ((row & 7) << 4);
      async16(Ab + (size_t)(m0 + row) * Kb + kk * 128 + sw, sa + p * 4096 + w * 1024);
      async16(Wb + (size_t)(n0 + row) * Kb + kk * 128 + sw, sb + p * 4096 + w * 1024);
    }
    __syncthreads();
    #pragma unroll
    for (int ks = 0; ks < 2; ++ks) {
      short8v af[4], bfr[4];
      #pragma unroll
      for (int mf = 0; mf < 4; ++mf) {
        int r = wr * 64 + mf * 16 + ln15;
        af[mf] = *(const short8v*)(sa + r * 128 + ((ks * 64 + gq * 16) ^ ((r & 7) << 4)));
      }
      #pragma unroll
      for (int nf = 0; nf < 4; ++nf) {
        int r = wc * 64 + nf * 16 + ln15;
        bfr[nf] = *(const short8v*)(sb + r * 128 + ((ks * 64 + gq * 16) ^ ((r & 7) << 4)));
      }
      #pragma unroll
      for (int mf = 0; mf < 4; ++mf)
        #pragma unroll
        for (int nf = 0; nf < 4; ++nf)
          acc[mf][nf] = mfma32(af[mf], bfr[nf], acc[mf][nf]);
    }
    __syncthreads();
  }
  #pragma unroll
  for (int nf = 0; nf < 4; ++nf) {
    int col = n0 + wc * 64 + nf * 16 + ln15;
    float bb = bias[col];
    #pragma unroll
    for (int mf = 0; mf < 4; ++mf) {
      int rb = m0 + wr * 64 + mf * 16 + 4 * gq;
      #pragma unroll
      for (int j = 0; j < 4; ++j) {
        size_t idx = (size_t)(rb + j) * N + col;
        float v = acc[mf][nf][j] + bb;
        if (RESID) v += resid[idx];
        out[idx] = f2bf(v);
      }
    }
  }
}

// ---------------- merged K/V projection GEMM ----------------
// A: [M][256] bf16, Wt: stacked [512][256] ([0:256)=Wk^T, [256:512)=Wv^T).
// col<256 -> Kout, else Vout (both [M][256]).
__global__ __launch_bounds__(256, 2)
void gemm_kv(const u16* __restrict__ A, const u16* __restrict__ Wt,
             const float* __restrict__ bk, const float* __restrict__ bv,
             u16* __restrict__ Kout, u16* __restrict__ Vout) {
  __shared__ alignas(16) char sm[32768];
  char* sa = sm;
  char* sb = sm + 16384;
  const int tid = threadIdx.x;
  const int w = tid >> 6, lane = tid & 63;
  const int ln15 = lane & 15, gq = lane >> 4;
  const int wr = w >> 1, wc = w & 1;
  const int m0 = blockIdx.x * 128, n0 = blockIdx.y * 128;
  const char* Ab = (const char*)A;
  const char* Wb = (const char*)Wt;

  float4v acc[4][4] = {};
  for (int kk = 0; kk < 4; ++kk) {
    #pragma unroll
    for (int p = 0; p < 4; ++p) {
      int L = p * 4096 + w * 1024 + lane * 16;
      int row = L >> 7, colb = L & 127;
      int sw = colb ^ ((row & 7) << 4);
      async16(Ab + (size_t)(m0 + row) * 512 + kk * 128 + sw, sa + p * 4096 + w * 1024);
      async16(Wb + (size_t)(n0 + row) * 512 + kk * 128 + sw, sb + p * 4096 + w * 1024);
    }
    __syncthreads();
    #pragma unroll
    for (int ks = 0; ks < 2; ++ks) {
      short8v af[4], bfr[4];
      #pragma unroll
      for (int mf = 0; mf < 4; ++mf) {
        int r = wr * 64 + mf * 16 + ln15;
        af[mf] = *(const short8v*)(sa + r * 128 + ((ks * 64 + gq * 16) ^ ((r & 7) << 4)));
      }
      #pragma unroll
      for (int nf = 0; nf < 4; ++nf) {
        int r = wc * 64 + nf * 16 + ln15;
        bfr[nf] = *(const short8v*)(sb + r * 128 + ((ks * 64 + gq * 16) ^ ((r & 7) << 4)));
      }
      #pragma unroll
      for (int mf = 0; mf < 4; ++mf)
        #pragma unroll
        for (int nf = 0; nf < 4; ++nf)
          acc[mf][nf] = mfma32(af[mf], bfr[nf], acc[mf][nf]);
    }
    __syncthreads();
  }
  #pragma unroll
  for (int nf = 0; nf < 4; ++nf) {
    int col = n0 + wc * 64 + nf * 16 + ln15;  // 0..511
    const bool isK = col < 256;
    const int c2 = isK ? col : col - 256;
    u16* outp = isK ? Kout : Vout;
    float bb = isK ? bk[c2] : bv[c2];
    #pragma unroll
    for (int mf = 0; mf < 4; ++mf) {
      int rb = m0 + wr * 64 + mf * 16 + 4 * gq;
      #pragma unroll
      for (int j = 0; j < 4; ++j)
        outp[(size_t)(rb + j) * 256 + c2] = f2bf(acc[mf][nf][j] + bb);
    }
  }
}

// ---------------- windowed attention, one block per (window, head, q-half) ----------------
// Q,K,V: [65536][256] bf16 (head slice at h*32). ctx out same layout.
__global__ __launch_bounds__(256, 2)
void attn_kernel(const u16* __restrict__ Qg, const u16* __restrict__ Kg,
                 const u16* __restrict__ Vg, u16* __restrict__ ctx) {
  __shared__ alignas(16) char vs[256 * 80];  // V tile, 80B padded rows (conflict-free)
  const int bw = blockIdx.x;
  const int win = bw >> 4, head = (bw >> 1) & 7, qh = bw & 1;
  const int tid = threadIdx.x;
  const int w = tid >> 6, lane = tid & 63;
  const int ln15 = lane & 15, gq = lane >> 4;
  const int tok0 = win << 8;
  const int q0 = qh * 128 + w * 32;

  // stage V [256][32] into padded LDS
  {
    const u16* src = Vg + (size_t)(tok0 + tid) * 256 + head * 32;
    char* dst = vs + tid * 80;
    #pragma unroll
    for (int i = 0; i < 4; ++i)
      *(short8v*)(dst + i * 16) = *(const short8v*)(src + i * 8);
  }

  // Q B-fragments (2 x 16 q-cols), direct from global
  short8v qf[2];
  #pragma unroll
  for (int qi = 0; qi < 2; ++qi)
    qf[qi] = *(const short8v*)(Qg + (size_t)(tok0 + q0 + qi * 16 + ln15) * 256 + head * 32 + gq * 8);

  // S^T = K @ Q^T  (16 key-frags x 2 q-frags), dh=32 -> single MFMA each
  float4v s[16][2];
  #pragma unroll
  for (int kf = 0; kf < 16; ++kf) {
    short8v kfr = *(const short8v*)(Kg + (size_t)(tok0 + kf * 16 + ln15) * 256 + head * 32 + gq * 8);
    float4v z = {0.f, 0.f, 0.f, 0.f};
    s[kf][0] = mfma32(kfr, qf[0], z);
    s[kf][1] = mfma32(kfr, qf[1], z);
  }
  __syncthreads();  // V staged

  // softmax over k (rows of S^T): per-lane 64 vals + 4-lane reduce (xor 16,32)
  const float KSC = (float)(1.4426950408889634 / 5.656854249492381);  // log2e/sqrt(32)
  float rs[2];
  #pragma unroll
  for (int qi = 0; qi < 2; ++qi) {
    float mx = -1e30f;
    #pragma unroll
    for (int kf = 0; kf < 16; ++kf)
      #pragma unroll
      for (int j = 0; j < 4; ++j) mx = fmaxf(mx, s[kf][qi][j]);
    mx = fmaxf(mx, __shfl_xor(mx, 16));
    mx = fmaxf(mx, __shfl_xor(mx, 32));
    float sum = 0.f;
    #pragma unroll
    for (int kf = 0; kf < 16; ++kf)
      #pragma unroll
      for (int j = 0; j < 4; ++j) {
        float p = exp2f((s[kf][qi][j] - mx) * KSC);
        s[kf][qi][j] = p;
        sum += p;
      }
    sum += __shfl_xor(sum, 16);
    sum += __shfl_xor(sum, 32);
    rs[qi] = 1.0f / sum;
  }

  // ctx^T = V^T @ P^T via 16x16x16 (P^T frags feed B-operand lane-for-lane)
  float4v cacc[2][2] = {};  // [df][qi]
  #pragma unroll
  for (int ks = 0; ks < 16; ++ks) {
    short4v pb[2];
    pb[0] = cvt4(s[ks][0]);
    pb[1] = cvt4(s[ks][1]);
    #pragma unroll
    for (int df = 0; df < 2; ++df) {
      const char* vb = vs + (size_t)(16 * ks + 4 * gq) * 80 + (df * 16 + ln15) * 2;
      short4v va;
      va[0] = *(const short*)(vb);
      va[1] = *(const short*)(vb + 80);
      va[2] = *(const short*)(vb + 160);
      va[3] = *(const short*)(vb + 240);
      cacc[df][0] = mfma16(va, pb[0], cacc[df][0]);
      cacc[df][1] = mfma16(va, pb[1], cacc[df][1]);
    }
  }

  // scale by 1/sum and store (d contiguous 4 -> 8B stores)
  #pragma unroll
  for (int qi = 0; qi < 2; ++qi)
    #pragma unroll
    for (int df = 0; df < 2; ++df) {
      short4v o;
      #pragma unroll
      for (int j = 0; j < 4; ++j) o[j] = (short)f2bf(cacc[df][qi][j] * rs[qi]);
      *(short4v*)(ctx + (size_t)(tok0 + q0 + qi * 16 + ln15) * 256 + head * 32 + df * 16 + 4 * gq) = o;
    }
}

// ---------------- row-wise LayerNorm in place (bf16), one wave per row ----------------
__global__ __launch_bounds__(256, 4)
void ln_rows(u16* __restrict__ x, const float* __restrict__ g, const float* __restrict__ b) {
  int row = blockIdx.x * 4 + (threadIdx.x >> 6);
  int lane = threadIdx.x & 63;
  u16* p = x + (size_t)row * 256 + lane * 4;
  short4v v = *(short4v*)p;
  float f[4];
  #pragma unroll
  for (int i = 0; i < 4; ++i) f[i] = bf2f((unsigned short)v[i]);
  float s = f[0] + f[1] + f[2] + f[3];
  float ss = f[0] * f[0] + f[1] * f[1] + f[2] * f[2] + f[3] * f[3];
  #pragma unroll
  for (int m = 1; m <= 32; m <<= 1) {
    s += __shfl_xor(s, m);
    ss += __shfl_xor(ss, m);
  }
  float mu = s * (1.f / 256.f);
  float var = ss * (1.f / 256.f) - mu * mu;
  float rstd = rsqrtf(var + 1e-5f);
  #pragma unroll
  for (int i = 0; i < 4; ++i) {
    int c = lane * 4 + i;
    float o = (f[i] - mu) * rstd * g[c] + b[c];
    v[i] = (short)f2bf(o);
  }
  *(short4v*)p = v;
}

// ---------------- fused FFN v6 + residual + LN2 ----------------
// out = LN2(x + relu(x@W1+b1)@W2 + b2). 512 threads, 256 rows/block; wave owns
// 32 rows; x and h1 in registers. GEMM2 now mfma32 against k-permuted W2t
// (perm f'(p) baked into cvt_wT), W2 chunk reg-staged into 80B-padded rows.
// Double-buffered, T14 load-early/write-late, 1 barrier/chunk.
__global__ __launch_bounds__(512, 2)
void ffn_v6(const u16* __restrict__ X, const u16* __restrict__ W1t,
            const u16* __restrict__ W2tp, const float* __restrict__ b1,
            const float* __restrict__ b2, const float* __restrict__ g2,
            const float* __restrict__ be2, float* __restrict__ out) {
  __shared__ alignas(16) char w1c[2][16384];   // [32 f][512B k], XOR-swizzled
  __shared__ alignas(16) char w2c[2][20480];   // [256 n][80B] (64B data + 16 pad)
  __shared__ alignas(16) float b1s[1024];
  const int tid = threadIdx.x;  // 0..511
  const int w = tid >> 6, lane = tid & 63;
  const int ln15 = lane & 15, gq = lane >> 4;
  const int m0 = blockIdx.x * 256;
  const int wrow0 = m0 + w * 32;

  b1s[tid] = b1[tid];
  b1s[tid + 512] = b1[tid + 512];

  // x rows in registers (B-frags for swapped GEMM1): 2 col-tiles x 8 k-chunks
  short8v xr[2][8];
  #pragma unroll
  for (int ct = 0; ct < 2; ++ct)
    #pragma unroll
    for (int kc = 0; kc < 8; ++kc)
      xr[ct][kc] = *(const short8v*)(X + (size_t)(wrow0 + ct * 16 + ln15) * 256 + kc * 32 + gq * 8);

  float4v ff[2][16] = {};  // [ct][nt]: col = nt*16+ln15, row = wrow0+ct*16+4gq+j
  short8v w2r[2];          // W2 chunk staging regs

  const char* W1b = (const char*)W1t;
  const char* W2b = (const char*)W2tp;

  // ---- staging helpers (c = chunk index 0..31); 512 threads -> 2 x 16B each ----
  #define STAGE_W1(buf, c)                                                     \
    {                                                                          \
      _Pragma("unroll")                                                        \
      for (int p = 0; p < 2; ++p) {                                            \
        int L = p * 8192 + tid * 16;                                           \
        int r = L >> 9, colb = L & 511;                                        \
        async16(W1b + (size_t)((c) * 32 + r) * 512 + (colb ^ ((r & 7) << 4)),  \
                w1c[buf] + L);                                                 \
      }                                                                        \
    }
  #define LOAD_W2(c)                                                           \
    {                                                                          \
      _Pragma("unroll")                                                        \
      for (int p = 0; p < 2; ++p) {                                            \
        int idx = p * 8192 + tid * 16;                                         \
        int n = idx >> 6, off = idx & 63;                                      \
        w2r[p] = *(const short8v*)(W2b + (size_t)n * 2048 + (c) * 64 + off);   \
      }                                                                        \
    }
  #define WRITE_W2(buf)                                                        \
    {                                                                          \
      _Pragma("unroll")                                                        \
      for (int p = 0; p < 2; ++p) {                                            \
        int idx = p * 8192 + tid * 16;                                         \
        int n = idx >> 6, off = idx & 63;                                      \
        *(short8v*)(w2c[buf] + n * 80 + off) = w2r[p];                         \
      }                                                                        \
    }

  STAGE_W1(0, 0);
  LOAD_W2(0);
  WRITE_W2(0);
  __syncthreads();

  #pragma unroll 2
  for (int c = 0; c < 32; ++c) {
    const int buf = c & 1;
    if (c < 31) {
      STAGE_W1(buf ^ 1, c + 1);
      LOAD_W2(c + 1);
    }

    // GEMM1 (swapped): h1^T[f-tile][xrow] = W1chunk @ x^T, k = 256
    float4v g1[2][2] = {};  // [ct][ft]
    #pragma unroll
    for (int kc = 0; kc < 8; ++kc) {
      #pragma unroll
      for (int ft = 0; ft < 2; ++ft) {
        int r = ft * 16 + ln15;
        short8v a = *(const short8v*)(w1c[buf] + r * 512 +
                                      ((kc * 64 + gq * 16) ^ ((r & 7) << 4)));
        g1[0][ft] = mfma32(a, xr[0][kc], g1[0][ft]);
        g1[1][ft] = mfma32(a, xr[1][kc], g1[1][ft]);
      }
    }
    // bias + relu + pack into mfma32 A-frag: slot e = ft*4+j holds physical
    // f = c*32 + 16*ft + 4*gq + j  == W2tp position p = 8*gq + e  (perm'd)
    short8v pa8[2];  // [ct]
    #pragma unroll
    for (int ft = 0; ft < 2; ++ft) {
      float4v bv4 = *(const float4v*)(b1s + c * 32 + ft * 16 + 4 * gq);
      #pragma unroll
      for (int ct = 0; ct < 2; ++ct)
        #pragma unroll
        for (int j = 0; j < 4; ++j) {
          float v = g1[ct][ft][j] + bv4[j];
          v = v > 0.f ? v : 0.f;
          pa8[ct][ft * 4 + j] = (short)f2bf(v);
        }
    }
    // GEMM2: ff += h1 @ W2chunk (one mfma32 per nt per ct; K=32 = whole chunk)
    #pragma unroll
    for (int nt = 0; nt < 16; ++nt) {
      short8v wb = *(const short8v*)(w2c[buf] + (nt * 16 + ln15) * 80 + gq * 16);
      ff[0][nt] = mfma32(pa8[0], wb, ff[0][nt]);
      ff[1][nt] = mfma32(pa8[1], wb, ff[1][nt]);
    }

    if (c < 31) WRITE_W2(buf ^ 1);
    __syncthreads();
  }

  // ---- epilogue: + b2 + x residual, LN2 per row (16-lane reduce), f32 out ----
  #pragma unroll
  for (int ct = 0; ct < 2; ++ct)
    #pragma unroll
    for (int j = 0; j < 4; ++j) {
      int r2 = wrow0 + ct * 16 + 4 * gq + j;
      float sum = 0.f, sq = 0.f;
      float vv[16];
      #pragma unroll
      for (int nt = 0; nt < 16; ++nt) {
        int col = nt * 16 + ln15;
        float xv = bf2f(X[(size_t)r2 * 256 + col]);
        float v = ff[ct][nt][j] + b2[col] + xv;
        vv[nt] = v;
        sum += v;
        sq += v * v;
      }
      #pragma unroll
      for (int m = 1; m <= 8; m <<= 1) {
        sum += __shfl_xor(sum, m);
        sq += __shfl_xor(sq, m);
      }
      float mu = sum * (1.f / 256.f);
      float var = sq * (1.f / 256.f) - mu * mu;
      float rstd = rsqrtf(var + 1e-5f);
      #pragma unroll
      for (int nt = 0; nt < 16; ++nt) {
        int col = nt * 16 + ln15;
        out[(size_t)r2 * 256 + col] = (vv[nt] - mu) * rstd * g2[col] + be2[col];
      }
    }
  #undef STAGE_W1
  #undef LOAD_W2
  #undef WRITE_W2
}

extern "C" void kernel_launch(void* const* d_in, const int* in_sizes, int n_in,
                              void* d_out, int out_size, void* d_ws, size_t ws_size,
                              hipStream_t stream) {
  (void)in_sizes; (void)n_in; (void)out_size;
  const float* query = (const float*)d_in[0];
  const float* kv    = (const float*)d_in[1];
  const float* Wqm = (const float*)d_in[2];  const float* bq = (const float*)d_in[3];
  const float* Wkm = (const float*)d_in[4];  const float* bk = (const float*)d_in[5];
  const float* Wvm = (const float*)d_in[6];  const float* bv = (const float*)d_in[7];
  const float* Wom = (const float*)d_in[8];  const float* bo = (const float*)d_in[9];
  const float* ln1g = (const float*)d_in[10]; const float* ln1b = (const float*)d_in[11];
  const float* W1m = (const float*)d_in[12]; const float* b1 = (const float*)d_in[13];
  const float* W2m = (const float*)d_in[14]; const float* b2 = (const float*)d_in[15];
  const float* ln2g = (const float*)d_in[16]; const float* ln2b = (const float*)d_in[17];
  float* out = (float*)d_out;

  char* ws = (char*)d_ws;
  const size_t MB = 1ull << 20;
  if (ws_size < 130 * MB) return;  // avoid OOB if workspace too small

  // lifetime-aliased layout (all bf16):
  u16* qbf  = (u16*)(ws);            // [0,32M)  input q bf16; dead after Q-proj
  u16* kvbf = (u16*)(ws + 32 * MB);  // [32,64M) input kv bf16; dead after V-proj
  u16* Vw   = (u16*)(ws);            // aliases qbf
  u16* ctxw = (u16*)(ws + 32 * MB);  // aliases kvbf
  u16* Qw   = (u16*)(ws + 64 * MB);  // dead after attn
  u16* xw   = (u16*)(ws + 64 * MB);  // aliases Qw
  u16* Kw   = (u16*)(ws + 96 * MB);
  char* wb = ws + 128 * MB;
  u16* Wqt = (u16*)(wb);
  u16* Wkt = (u16*)(wb + 131072);   // Wkt [256][256] and Wvt [256][256] are
  u16* Wvt = (u16*)(wb + 262144);   // contiguous -> stacked [512][256] at Wkt
  u16* Wot = (u16*)(wb + 393216);
  u16* W1t = (u16*)(wb + 524288);
  u16* W2t = (u16*)(wb + 1048576);

  cvt_in<<<dim3(8192, 2), 256, 0, stream>>>(query, kv, qbf, kvbf);
  cvt_wT<<<dim3(64, 6), 256, 0, stream>>>(Wqm, Wkm, Wvm, Wom, W1m, W2m,
                                          Wqt, Wkt, Wvt, Wot, W1t, W2t);
  gemm128<false><<<dim3(512, 2), 256, 0, stream>>>(qbf,  Wqt, bq, nullptr, Qw, 65536, 256, 256);
  gemm_kv<<<dim3(512, 4), 256, 0, stream>>>(kvbf, Wkt, bk, bv, Kw, Vw);
  attn_kernel<<<dim3(4096), 256, 0, stream>>>(Qw, Kw, Vw, ctxw);
  gemm128<true><<<dim3(512, 2), 256, 0, stream>>>(ctxw, Wot, bo, query, xw, 65536, 256, 256);
  ln_rows<<<dim3(16384), 256, 0, stream>>>(xw, ln1g, ln1b);
  ffn_v6<<<dim3(256), 512, 0, stream>>>(xw, W1t, W2t, b1, b2, ln2g, ln2b, out);
}

// Round 8
// 330.427 us; speedup vs baseline: 1.2270x; 1.0481x over previous
//
#include <hip/hip_runtime.h>

#define DEV __device__ __forceinline__

typedef short short4v __attribute__((ext_vector_type(4)));
typedef short short8v __attribute__((ext_vector_type(8)));
typedef float float4v __attribute__((ext_vector_type(4)));
typedef unsigned short u16;

#define S32E ((size_t)65536 * 32)   // head stride, elements (u16)
#define S64B ((size_t)65536 * 64)   // head stride, bytes

DEV unsigned short f2bf(float f) {
  unsigned u = __builtin_bit_cast(unsigned, f);
  u += 0x7fffu + ((u >> 16) & 1u);
  return (unsigned short)(u >> 16);
}
DEV float bf2f(unsigned short h) {
  unsigned u = ((unsigned)h) << 16;
  return __builtin_bit_cast(float, u);
}
DEV float4v mfma32(short8v a, short8v b, float4v c) {
  return __builtin_amdgcn_mfma_f32_16x16x32_bf16(a, b, c, 0, 0, 0);
}
DEV float4v mfma16(short4v a, short4v b, float4v c) {
  return __builtin_amdgcn_mfma_f32_16x16x16bf16_1k(a, b, c, 0, 0, 0);
}
DEV void async16(const void* g, void* l) {
  __builtin_amdgcn_global_load_lds(
      (const __attribute__((address_space(1))) unsigned*)g,
      (__attribute__((address_space(3))) unsigned*)l, 16, 0, 0);
}
DEV short4v cvt4(float4v v) {
  short4v r;
  r[0] = (short)f2bf(v[0]); r[1] = (short)f2bf(v[1]);
  r[2] = (short)f2bf(v[2]); r[3] = (short)f2bf(v[3]);
  return r;
}

// ---------------- input conversion f32 -> bf16 ----------------
__global__ __launch_bounds__(256)
void cvt_in(const float* __restrict__ q, const float* __restrict__ kv,
            u16* __restrict__ qb, u16* __restrict__ kvb) {
  const float* src = blockIdx.y ? kv : q;
  u16* dst = blockIdx.y ? kvb : qb;
  size_t i = ((size_t)blockIdx.x * 256 + threadIdx.x) * 8;
  float4v a = *(const float4v*)(src + i);
  float4v b = *(const float4v*)(src + i + 4);
  short8v o;
  o[0] = (short)f2bf(a[0]); o[1] = (short)f2bf(a[1]);
  o[2] = (short)f2bf(a[2]); o[3] = (short)f2bf(a[3]);
  o[4] = (short)f2bf(b[0]); o[5] = (short)f2bf(b[1]);
  o[6] = (short)f2bf(b[2]); o[7] = (short)f2bf(b[3]);
  *(short8v*)(dst + i) = o;
}

// ------------- weight convert + transpose (LDS-tiled, coalesced) -------------
__global__ __launch_bounds__(256)
void cvt_wT(const float* Wq, const float* Wk, const float* Wv, const float* Wo,
            const float* W1, const float* W2,
            u16* Wqt, u16* Wkt, u16* Wvt, u16* Wot, u16* W1t, u16* W2t) {
  __shared__ float ld[64 * 69];
  const float* src; u16* dst; int R, C; bool permk = false;
  switch (blockIdx.y) {
    case 0: src = Wq; dst = Wqt; R = 256;  C = 256;  break;
    case 1: src = Wk; dst = Wkt; R = 256;  C = 256;  break;
    case 2: src = Wv; dst = Wvt; R = 256;  C = 256;  break;
    case 3: src = Wo; dst = Wot; R = 256;  C = 256;  break;
    case 4: src = W1; dst = W1t; R = 256;  C = 1024; break;
    default: src = W2; dst = W2t; R = 1024; C = 256; permk = true; break;
  }
  const int ntile = (R >> 6) * (C >> 6);
  if ((int)blockIdx.x >= ntile) return;
  const int tf = blockIdx.x % (R >> 6);
  const int tn = blockIdx.x / (R >> 6);
  const int r0 = tf << 6, c0 = tn << 6;
  const int tid = threadIdx.x;
  {
    int lr = tid >> 4, lc = (tid & 15) << 2;
    #pragma unroll
    for (int ps = 0; ps < 4; ++ps) {
      int r = ps * 16 + lr;
      float4v v = *(const float4v*)(src + (size_t)(r0 + r) * C + c0 + lc);
      #pragma unroll
      for (int e = 0; e < 4; ++e) ld[r * 69 + lc + e] = v[e];
    }
  }
  __syncthreads();
  {
    int p8 = (tid & 7) << 3;
    #pragma unroll
    for (int ps = 0; ps < 2; ++ps) {
      int n = ps * 32 + (tid >> 3);
      short8v o;
      #pragma unroll
      for (int e = 0; e < 8; ++e) {
        int p = p8 + e;
        int fl = p;
        if (permk) {
          int m = p & 31;
          fl = (p & 32) + 16 * ((m >> 2) & 1) + 4 * (m >> 3) + (m & 3);
        }
        o[e] = (short)f2bf(ld[fl * 69 + n]);
      }
      *(short8v*)(dst + (size_t)(c0 + n) * R + r0 + p8) = o;
    }
  }
}

// ---------------- 128x128-tile GEMM: out = A @ Wt^T + bias (+resid) ----------------
// AHEAD: A is head-major [8][65536][32] (K must be 256). OHEAD: out head-major.
template<bool RESID, bool AHEAD, bool OHEAD>
__global__ __launch_bounds__(256, 2)
void gemm128(const u16* __restrict__ A, const u16* __restrict__ Wt,
             const float* __restrict__ bias, const float* __restrict__ resid,
             u16* __restrict__ out, int M, int N, int K) {
  __shared__ alignas(16) char sm[32768];
  char* sa = sm;
  char* sb = sm + 16384;
  const int tid = threadIdx.x;
  const int w = tid >> 6, lane = tid & 63;
  const int ln15 = lane & 15, gq = lane >> 4;
  const int wr = w >> 1, wc = w & 1;
  const int m0 = blockIdx.x * 128, n0 = blockIdx.y * 128;
  const char* Ab = (const char*)A;
  const char* Wb = (const char*)Wt;
  const int Kb = K * 2;  // row bytes

  float4v acc[4][4] = {};
  const int nk = K >> 6;
  for (int kk = 0; kk < nk; ++kk) {
    #pragma unroll
    for (int p = 0; p < 4; ++p) {
      int L = p * 4096 + w * 1024 + lane * 16;
      int row = L >> 7, colb = L & 127;
      int sw = colb ^ ((row & 7) << 4);
      if (AHEAD) {
        int b = kk * 128 + sw;  // logical byte within 512B row
        async16(Ab + (size_t)(b >> 6) * S64B + (size_t)(m0 + row) * 64 + (b & 63),
                sa + p * 4096 + w * 1024);
      } else {
        async16(Ab + (size_t)(m0 + row) * Kb + kk * 128 + sw, sa + p * 4096 + w * 1024);
      }
      async16(Wb + (size_t)(n0 + row) * Kb + kk * 128 + sw, sb + p * 4096 + w * 1024);
    }
    __syncthreads();
    #pragma unroll
    for (int ks = 0; ks < 2; ++ks) {
      short8v af[4], bfr[4];
      #pragma unroll
      for (int mf = 0; mf < 4; ++mf) {
        int r = wr * 64 + mf * 16 + ln15;
        af[mf] = *(const short8v*)(sa + r * 128 + ((ks * 64 + gq * 16) ^ ((r & 7) << 4)));
      }
      #pragma unroll
      for (int nf = 0; nf < 4; ++nf) {
        int r = wc * 64 + nf * 16 + ln15;
        bfr[nf] = *(const short8v*)(sb + r * 128 + ((ks * 64 + gq * 16) ^ ((r & 7) << 4)));
      }
      #pragma unroll
      for (int mf = 0; mf < 4; ++mf)
        #pragma unroll
        for (int nf = 0; nf < 4; ++nf)
          acc[mf][nf] = mfma32(af[mf], bfr[nf], acc[mf][nf]);
    }
    __syncthreads();
  }
  #pragma unroll
  for (int nf = 0; nf < 4; ++nf) {
    int col = n0 + wc * 64 + nf * 16 + ln15;
    float bb = bias[col];
    #pragma unroll
    for (int mf = 0; mf < 4; ++mf) {
      int rb = m0 + wr * 64 + mf * 16 + 4 * gq;
      #pragma unroll
      for (int j = 0; j < 4; ++j) {
        float v = acc[mf][nf][j] + bb;
        if (RESID) v += resid[(size_t)(rb + j) * N + col];
        if (OHEAD)
          out[(size_t)(col >> 5) * S32E + (size_t)(rb + j) * 32 + (col & 31)] = f2bf(v);
        else
          out[(size_t)(rb + j) * N + col] = f2bf(v);
      }
    }
  }
}

// ---------------- merged K/V projection GEMM (head-major outputs) ----------------
__global__ __launch_bounds__(256, 2)
void gemm_kv(const u16* __restrict__ A, const u16* __restrict__ Wt,
             const float* __restrict__ bk, const float* __restrict__ bv,
             u16* __restrict__ Kout, u16* __restrict__ Vout) {
  __shared__ alignas(16) char sm[32768];
  char* sa = sm;
  char* sb = sm + 16384;
  const int tid = threadIdx.x;
  const int w = tid >> 6, lane = tid & 63;
  const int ln15 = lane & 15, gq = lane >> 4;
  const int wr = w >> 1, wc = w & 1;
  const int m0 = blockIdx.x * 128, n0 = blockIdx.y * 128;
  const char* Ab = (const char*)A;
  const char* Wb = (const char*)Wt;

  float4v acc[4][4] = {};
  for (int kk = 0; kk < 4; ++kk) {
    #pragma unroll
    for (int p = 0; p < 4; ++p) {
      int L = p * 4096 + w * 1024 + lane * 16;
      int row = L >> 7, colb = L & 127;
      int sw = colb ^ ((row & 7) << 4);
      async16(Ab + (size_t)(m0 + row) * 512 + kk * 128 + sw, sa + p * 4096 + w * 1024);
      async16(Wb + (size_t)(n0 + row) * 512 + kk * 128 + sw, sb + p * 4096 + w * 1024);
    }
    __syncthreads();
    #pragma unroll
    for (int ks = 0; ks < 2; ++ks) {
      short8v af[4], bfr[4];
      #pragma unroll
      for (int mf = 0; mf < 4; ++mf) {
        int r = wr * 64 + mf * 16 + ln15;
        af[mf] = *(const short8v*)(sa + r * 128 + ((ks * 64 + gq * 16) ^ ((r & 7) << 4)));
      }
      #pragma unroll
      for (int nf = 0; nf < 4; ++nf) {
        int r = wc * 64 + nf * 16 + ln15;
        bfr[nf] = *(const short8v*)(sb + r * 128 + ((ks * 64 + gq * 16) ^ ((r & 7) << 4)));
      }
      #pragma unroll
      for (int mf = 0; mf < 4; ++mf)
        #pragma unroll
        for (int nf = 0; nf < 4; ++nf)
          acc[mf][nf] = mfma32(af[mf], bfr[nf], acc[mf][nf]);
    }
    __syncthreads();
  }
  #pragma unroll
  for (int nf = 0; nf < 4; ++nf) {
    int col = n0 + wc * 64 + nf * 16 + ln15;  // 0..511
    const bool isK = col < 256;
    const int c2 = col & 255;
    u16* outp = isK ? Kout : Vout;
    float bb = isK ? bk[c2] : bv[c2];
    const size_t hb = (size_t)(c2 >> 5) * S32E;
    const int d = c2 & 31;
    #pragma unroll
    for (int mf = 0; mf < 4; ++mf) {
      int rb = m0 + wr * 64 + mf * 16 + 4 * gq;
      #pragma unroll
      for (int j = 0; j < 4; ++j)
        outp[hb + (size_t)(rb + j) * 32 + d] = f2bf(acc[mf][nf][j] + bb);
    }
  }
}

// ---------------- windowed attention v2: one block per (window, head) ----------------
// Q,K,V,ctx head-major [8][65536][32] bf16. K,V staged once in LDS (80B-padded
// rows, proven conflict-free); each wave does 2 passes x 32 q-rows.
__global__ __launch_bounds__(256, 2)
void attn_v2(const u16* __restrict__ Qg, const u16* __restrict__ Kg,
             const u16* __restrict__ Vg, u16* __restrict__ ctx) {
  __shared__ alignas(16) char ks[256 * 80];
  __shared__ alignas(16) char vs[256 * 80];
  const int bw = blockIdx.x;
  const int win = bw >> 3, head = bw & 7;
  const int tid = threadIdx.x;
  const int w = tid >> 6, lane = tid & 63;
  const int ln15 = lane & 15, gq = lane >> 4;
  const int tok0 = win << 8;
  const u16* Qh = Qg + head * S32E + (size_t)tok0 * 32;
  const u16* Kh = Kg + head * S32E + (size_t)tok0 * 32;
  const u16* Vh = Vg + head * S32E + (size_t)tok0 * 32;
  u16* Ch = ctx + head * S32E + (size_t)tok0 * 32;

  // stage K,V [256][32] -> [256][80B] LDS (dense 16B loads, conflict-free writes)
  #pragma unroll
  for (int i = 0; i < 4; ++i) {
    int L = i * 4096 + tid * 16;
    int row = L >> 6, colb = L & 63;
    short8v kv0 = *(const short8v*)((const char*)Kh + L);
    short8v vv0 = *(const short8v*)((const char*)Vh + L);
    *(short8v*)(ks + row * 80 + colb) = kv0;
    *(short8v*)(vs + row * 80 + colb) = vv0;
  }
  __syncthreads();

  const float KSC = (float)(1.4426950408889634 / 5.656854249492381);  // log2e/sqrt(32)

  for (int pass = 0; pass < 2; ++pass) {
    const int q0 = w * 64 + pass * 32;

    // Q B-fragments (2 x 16 q-cols), contiguous head-major global reads
    short8v qf[2];
    #pragma unroll
    for (int qi = 0; qi < 2; ++qi)
      qf[qi] = *(const short8v*)(Qh + (size_t)(q0 + qi * 16 + ln15) * 32 + gq * 8);

    // S^T = K @ Q^T (16 key-frags x 2 q-frags), K from LDS
    float4v s[16][2];
    #pragma unroll
    for (int kf = 0; kf < 16; ++kf) {
      short8v kfr = *(const short8v*)(ks + (16 * kf + ln15) * 80 + gq * 16);
      float4v z = {0.f, 0.f, 0.f, 0.f};
      s[kf][0] = mfma32(kfr, qf[0], z);
      s[kf][1] = mfma32(kfr, qf[1], z);
    }

    // softmax over k: per-lane 64 vals + 4-lane-group reduce (xor 16,32)
    float rs[2];
    #pragma unroll
    for (int qi = 0; qi < 2; ++qi) {
      float mx = -1e30f;
      #pragma unroll
      for (int kf = 0; kf < 16; ++kf)
        #pragma unroll
        for (int j = 0; j < 4; ++j) mx = fmaxf(mx, s[kf][qi][j]);
      mx = fmaxf(mx, __shfl_xor(mx, 16));
      mx = fmaxf(mx, __shfl_xor(mx, 32));
      float mk = mx * KSC;
      float sum = 0.f;
      #pragma unroll
      for (int kf = 0; kf < 16; ++kf)
        #pragma unroll
        for (int j = 0; j < 4; ++j) {
          float p = exp2f(fmaf(s[kf][qi][j], KSC, -mk));
          s[kf][qi][j] = p;
          sum += p;
        }
      sum += __shfl_xor(sum, 16);
      sum += __shfl_xor(sum, 32);
      rs[qi] = 1.0f / sum;
    }

    // ctx^T = V^T @ P^T via 16x16x16 (P^T frags feed B-operand lane-for-lane)
    float4v cacc[2][2] = {};  // [df][qi]
    #pragma unroll
    for (int kss = 0; kss < 16; ++kss) {
      short4v pb[2];
      pb[0] = cvt4(s[kss][0]);
      pb[1] = cvt4(s[kss][1]);
      #pragma unroll
      for (int df = 0; df < 2; ++df) {
        const char* vb = vs + (size_t)(16 * kss + 4 * gq) * 80 + (df * 16 + ln15) * 2;
        short4v va;
        va[0] = *(const short*)(vb);
        va[1] = *(const short*)(vb + 80);
        va[2] = *(const short*)(vb + 160);
        va[3] = *(const short*)(vb + 240);
        cacc[df][0] = mfma16(va, pb[0], cacc[df][0]);
        cacc[df][1] = mfma16(va, pb[1], cacc[df][1]);
      }
    }

    // scale by 1/sum and store (d contiguous 4 -> 8B stores, head-major)
    #pragma unroll
    for (int qi = 0; qi < 2; ++qi)
      #pragma unroll
      for (int df = 0; df < 2; ++df) {
        short4v o;
        #pragma unroll
        for (int j = 0; j < 4; ++j) o[j] = (short)f2bf(cacc[df][qi][j] * rs[qi]);
        *(short4v*)(Ch + (size_t)(q0 + qi * 16 + ln15) * 32 + df * 16 + 4 * gq) = o;
      }
  }
}

// ---------------- row-wise LayerNorm in place (bf16), one wave per row ----------------
__global__ __launch_bounds__(256, 4)
void ln_rows(u16* __restrict__ x, const float* __restrict__ g, const float* __restrict__ b) {
  int row = blockIdx.x * 4 + (threadIdx.x >> 6);
  int lane = threadIdx.x & 63;
  u16* p = x + (size_t)row * 256 + lane * 4;
  short4v v = *(short4v*)p;
  float f[4];
  #pragma unroll
  for (int i = 0; i < 4; ++i) f[i] = bf2f((unsigned short)v[i]);
  float s = f[0] + f[1] + f[2] + f[3];
  float ss = f[0] * f[0] + f[1] * f[1] + f[2] * f[2] + f[3] * f[3];
  #pragma unroll
  for (int m = 1; m <= 32; m <<= 1) {
    s += __shfl_xor(s, m);
    ss += __shfl_xor(ss, m);
  }
  float mu = s * (1.f / 256.f);
  float var = ss * (1.f / 256.f) - mu * mu;
  float rstd = rsqrtf(var + 1e-5f);
  #pragma unroll
  for (int i = 0; i < 4; ++i) {
    int c = lane * 4 + i;
    float o = (f[i] - mu) * rstd * g[c] + b[c];
    v[i] = (short)f2bf(o);
  }
  *(short4v*)p = v;
}

// ---------------- fused FFN v6 + residual + LN2 ----------------
__global__ __launch_bounds__(512, 2)
void ffn_v6(const u16* __restrict__ X, const u16* __restrict__ W1t,
            const u16* __restrict__ W2tp, const float* __restrict__ b1,
            const float* __restrict__ b2, const float* __restrict__ g2,
            const float* __restrict__ be2, float* __restrict__ out) {
  __shared__ alignas(16) char w1c[2][16384];   // [32 f][512B k], XOR-swizzled
  __shared__ alignas(16) char w2c[2][20480];   // [256 n][80B] (64B data + 16 pad)
  __shared__ alignas(16) float b1s[1024];
  const int tid = threadIdx.x;  // 0..511
  const int w = tid >> 6, lane = tid & 63;
  const int ln15 = lane & 15, gq = lane >> 4;
  const int m0 = blockIdx.x * 256;
  const int wrow0 = m0 + w * 32;

  b1s[tid] = b1[tid];
  b1s[tid + 512] = b1[tid + 512];

  short8v xr[2][8];
  #pragma unroll
  for (int ct = 0; ct < 2; ++ct)
    #pragma unroll
    for (int kc = 0; kc < 8; ++kc)
      xr[ct][kc] = *(const short8v*)(X + (size_t)(wrow0 + ct * 16 + ln15) * 256 + kc * 32 + gq * 8);

  float4v ff[2][16] = {};
  short8v w2r[2];

  const char* W1b = (const char*)W1t;
  const char* W2b = (const char*)W2tp;

  #define STAGE_W1(buf, c)                                                     \
    {                                                                          \
      _Pragma("unroll")                                                        \
      for (int p = 0; p < 2; ++p) {                                            \
        int L = p * 8192 + tid * 16;                                           \
        int r = L >> 9, colb = L & 511;                                        \
        async16(W1b + (size_t)((c) * 32 + r) * 512 + (colb ^ ((r & 7) << 4)),  \
                w1c[buf] + L);                                                 \
      }                                                                        \
    }
  #define LOAD_W2(c)                                                           \
    {                                                                          \
      _Pragma("unroll")                                                        \
      for (int p = 0; p < 2; ++p) {                                            \
        int idx = p * 8192 + tid * 16;                                         \
        int n = idx >> 6, off = idx & 63;                                      \
        w2r[p] = *(const short8v*)(W2b + (size_t)n * 2048 + (c) * 64 + off);   \
      }                                                                        \
    }
  #define WRITE_W2(buf)                                                        \
    {                                                                          \
      _Pragma("unroll")                                                        \
      for (int p = 0; p < 2; ++p) {                                            \
        int idx = p * 8192 + tid * 16;                                         \
        int n = idx >> 6, off = idx & 63;                                      \
        *(short8v*)(w2c[buf] + n * 80 + off) = w2r[p];                         \
      }                                                                        \
    }

  STAGE_W1(0, 0);
  LOAD_W2(0);
  WRITE_W2(0);
  __syncthreads();

  #pragma unroll 2
  for (int c = 0; c < 32; ++c) {
    const int buf = c & 1;
    if (c < 31) {
      STAGE_W1(buf ^ 1, c + 1);
      LOAD_W2(c + 1);
    }

    float4v g1[2][2] = {};
    #pragma unroll
    for (int kc = 0; kc < 8; ++kc) {
      #pragma unroll
      for (int ft = 0; ft < 2; ++ft) {
        int r = ft * 16 + ln15;
        short8v a = *(const short8v*)(w1c[buf] + r * 512 +
                                      ((kc * 64 + gq * 16) ^ ((r & 7) << 4)));
        g1[0][ft] = mfma32(a, xr[0][kc], g1[0][ft]);
        g1[1][ft] = mfma32(a, xr[1][kc], g1[1][ft]);
      }
    }
    short8v pa8[2];
    #pragma unroll
    for (int ft = 0; ft < 2; ++ft) {
      float4v bv4 = *(const float4v*)(b1s + c * 32 + ft * 16 + 4 * gq);
      #pragma unroll
      for (int ct = 0; ct < 2; ++ct)
        #pragma unroll
        for (int j = 0; j < 4; ++j) {
          float v = g1[ct][ft][j] + bv4[j];
          v = v > 0.f ? v : 0.f;
          pa8[ct][ft * 4 + j] = (short)f2bf(v);
        }
    }
    #pragma unroll
    for (int nt = 0; nt < 16; ++nt) {
      short8v wb = *(const short8v*)(w2c[buf] + (nt * 16 + ln15) * 80 + gq * 16);
      ff[0][nt] = mfma32(pa8[0], wb, ff[0][nt]);
      ff[1][nt] = mfma32(pa8[1], wb, ff[1][nt]);
    }

    if (c < 31) WRITE_W2(buf ^ 1);
    __syncthreads();
  }

  #pragma unroll
  for (int ct = 0; ct < 2; ++ct)
    #pragma unroll
    for (int j = 0; j < 4; ++j) {
      int r2 = wrow0 + ct * 16 + 4 * gq + j;
      float sum = 0.f, sq = 0.f;
      float vv[16];
      #pragma unroll
      for (int nt = 0; nt < 16; ++nt) {
        int col = nt * 16 + ln15;
        float xv = bf2f(X[(size_t)r2 * 256 + col]);
        float v = ff[ct][nt][j] + b2[col] + xv;
        vv[nt] = v;
        sum += v;
        sq += v * v;
      }
      #pragma unroll
      for (int m = 1; m <= 8; m <<= 1) {
        sum += __shfl_xor(sum, m);
        sq += __shfl_xor(sq, m);
      }
      float mu = sum * (1.f / 256.f);
      float var = sq * (1.f / 256.f) - mu * mu;
      float rstd = rsqrtf(var + 1e-5f);
      #pragma unroll
      for (int nt = 0; nt < 16; ++nt) {
        int col = nt * 16 + ln15;
        out[(size_t)r2 * 256 + col] = (vv[nt] - mu) * rstd * g2[col] + be2[col];
      }
    }
  #undef STAGE_W1
  #undef LOAD_W2
  #undef WRITE_W2
}

extern "C" void kernel_launch(void* const* d_in, const int* in_sizes, int n_in,
                              void* d_out, int out_size, void* d_ws, size_t ws_size,
                              hipStream_t stream) {
  (void)in_sizes; (void)n_in; (void)out_size;
  const float* query = (const float*)d_in[0];
  const float* kv    = (const float*)d_in[1];
  const float* Wqm = (const float*)d_in[2];  const float* bq = (const float*)d_in[3];
  const float* Wkm = (const float*)d_in[4];  const float* bk = (const float*)d_in[5];
  const float* Wvm = (const float*)d_in[6];  const float* bv = (const float*)d_in[7];
  const float* Wom = (const float*)d_in[8];  const float* bo = (const float*)d_in[9];
  const float* ln1g = (const float*)d_in[10]; const float* ln1b = (const float*)d_in[11];
  const float* W1m = (const float*)d_in[12]; const float* b1 = (const float*)d_in[13];
  const float* W2m = (const float*)d_in[14]; const float* b2 = (const float*)d_in[15];
  const float* ln2g = (const float*)d_in[16]; const float* ln2b = (const float*)d_in[17];
  float* out = (float*)d_out;

  char* ws = (char*)d_ws;
  const size_t MB = 1ull << 20;
  if (ws_size < 130 * MB) return;

  // lifetime-aliased layout (all bf16); Q/K/V/ctx are head-major [8][65536][32]
  u16* qbf  = (u16*)(ws);            // input q bf16; dead after Q-proj
  u16* kvbf = (u16*)(ws + 32 * MB);  // input kv bf16; dead after V-proj
  u16* Vw   = (u16*)(ws);            // aliases qbf
  u16* ctxw = (u16*)(ws + 32 * MB);  // aliases kvbf
  u16* Qw   = (u16*)(ws + 64 * MB);  // dead after attn
  u16* xw   = (u16*)(ws + 64 * MB);  // aliases Qw
  u16* Kw   = (u16*)(ws + 96 * MB);
  char* wb = ws + 128 * MB;
  u16* Wqt = (u16*)(wb);
  u16* Wkt = (u16*)(wb + 131072);
  u16* Wvt = (u16*)(wb + 262144);
  u16* Wot = (u16*)(wb + 393216);
  u16* W1t = (u16*)(wb + 524288);
  u16* W2t = (u16*)(wb + 1048576);

  cvt_in<<<dim3(8192, 2), 256, 0, stream>>>(query, kv, qbf, kvbf);
  cvt_wT<<<dim3(64, 6), 256, 0, stream>>>(Wqm, Wkm, Wvm, Wom, W1m, W2m,
                                          Wqt, Wkt, Wvt, Wot, W1t, W2t);
  gemm128<false, false, true><<<dim3(512, 2), 256, 0, stream>>>(
      qbf, Wqt, bq, nullptr, Qw, 65536, 256, 256);
  gemm_kv<<<dim3(512, 4), 256, 0, stream>>>(kvbf, Wkt, bk, bv, Kw, Vw);
  attn_v2<<<dim3(2048), 256, 0, stream>>>(Qw, Kw, Vw, ctxw);
  gemm128<true, true, false><<<dim3(512, 2), 256, 0, stream>>>(
      ctxw, Wot, bo, query, xw, 65536, 256, 256);
  ln_rows<<<dim3(16384), 256, 0, stream>>>(xw, ln1g, ln1b);
  ffn_v6<<<dim3(256), 512, 0, stream>>>(xw, W1t, W2t, b1, b2, ln2g, ln2b, out);
}

// Round 10
// 303.416 us; speedup vs baseline: 1.3363x; 1.0890x over previous
//
#include <hip/hip_runtime.h>

#define DEV __device__ __forceinline__

typedef short short4v __attribute__((ext_vector_type(4)));
typedef short short8v __attribute__((ext_vector_type(8)));
typedef float float4v __attribute__((ext_vector_type(4)));
typedef unsigned short u16;

#define S32E ((size_t)65536 * 32)   // head stride, elements (u16)
#define S64B ((size_t)65536 * 64)   // head stride, bytes

DEV unsigned short f2bf(float f) {
  unsigned u = __builtin_bit_cast(unsigned, f);
  u += 0x7fffu + ((u >> 16) & 1u);
  return (unsigned short)(u >> 16);
}
DEV float bf2f(unsigned short h) {
  unsigned u = ((unsigned)h) << 16;
  return __builtin_bit_cast(float, u);
}
DEV float4v mfma32(short8v a, short8v b, float4v c) {
  return __builtin_amdgcn_mfma_f32_16x16x32_bf16(a, b, c, 0, 0, 0);
}
DEV float4v mfma16(short4v a, short4v b, float4v c) {
  return __builtin_amdgcn_mfma_f32_16x16x16bf16_1k(a, b, c, 0, 0, 0);
}
DEV void async16(const void* g, void* l) {
  __builtin_amdgcn_global_load_lds(
      (const __attribute__((address_space(1))) unsigned*)g,
      (__attribute__((address_space(3))) unsigned*)l, 16, 0, 0);
}
DEV short4v cvt4(float4v v) {
  short4v r;
  r[0] = (short)f2bf(v[0]); r[1] = (short)f2bf(v[1]);
  r[2] = (short)f2bf(v[2]); r[3] = (short)f2bf(v[3]);
  return r;
}

// ---------------- input conversion f32 -> bf16 ----------------
__global__ __launch_bounds__(256)
void cvt_in(const float* __restrict__ q, const float* __restrict__ kv,
            u16* __restrict__ qb, u16* __restrict__ kvb) {
  const float* src = blockIdx.y ? kv : q;
  u16* dst = blockIdx.y ? kvb : qb;
  size_t i = ((size_t)blockIdx.x * 256 + threadIdx.x) * 8;
  float4v a = *(const float4v*)(src + i);
  float4v b = *(const float4v*)(src + i + 4);
  short8v o;
  o[0] = (short)f2bf(a[0]); o[1] = (short)f2bf(a[1]);
  o[2] = (short)f2bf(a[2]); o[3] = (short)f2bf(a[3]);
  o[4] = (short)f2bf(b[0]); o[5] = (short)f2bf(b[1]);
  o[6] = (short)f2bf(b[2]); o[7] = (short)f2bf(b[3]);
  *(short8v*)(dst + i) = o;
}

// ------------- weight convert + transpose (LDS-tiled, coalesced) -------------
__global__ __launch_bounds__(256)
void cvt_wT(const float* Wq, const float* Wk, const float* Wv, const float* Wo,
            const float* W1, const float* W2,
            u16* Wqt, u16* Wkt, u16* Wvt, u16* Wot, u16* W1t, u16* W2t) {
  __shared__ float ld[64 * 69];
  const float* src; u16* dst; int R, C; bool permk = false;
  switch (blockIdx.y) {
    case 0: src = Wq; dst = Wqt; R = 256;  C = 256;  break;
    case 1: src = Wk; dst = Wkt; R = 256;  C = 256;  break;
    case 2: src = Wv; dst = Wvt; R = 256;  C = 256;  break;
    case 3: src = Wo; dst = Wot; R = 256;  C = 256;  break;
    case 4: src = W1; dst = W1t; R = 256;  C = 1024; break;
    default: src = W2; dst = W2t; R = 1024; C = 256; permk = true; break;
  }
  const int ntile = (R >> 6) * (C >> 6);
  if ((int)blockIdx.x >= ntile) return;
  const int tf = blockIdx.x % (R >> 6);
  const int tn = blockIdx.x / (R >> 6);
  const int r0 = tf << 6, c0 = tn << 6;
  const int tid = threadIdx.x;
  {
    int lr = tid >> 4, lc = (tid & 15) << 2;
    #pragma unroll
    for (int ps = 0; ps < 4; ++ps) {
      int r = ps * 16 + lr;
      float4v v = *(const float4v*)(src + (size_t)(r0 + r) * C + c0 + lc);
      #pragma unroll
      for (int e = 0; e < 4; ++e) ld[r * 69 + lc + e] = v[e];
    }
  }
  __syncthreads();
  {
    int p8 = (tid & 7) << 3;
    #pragma unroll
    for (int ps = 0; ps < 2; ++ps) {
      int n = ps * 32 + (tid >> 3);
      short8v o;
      #pragma unroll
      for (int e = 0; e < 8; ++e) {
        int p = p8 + e;
        int fl = p;
        if (permk) {
          int m = p & 31;
          fl = (p & 32) + 16 * ((m >> 2) & 1) + 4 * (m >> 3) + (m & 3);
        }
        o[e] = (short)f2bf(ld[fl * 69 + n]);
      }
      *(short8v*)(dst + (size_t)(c0 + n) * R + r0 + p8) = o;
    }
  }
}

// ---------------- 128x128-tile GEMM: out = A @ Wt^T + bias ----------------
// AHEAD: A is head-major [8][65536][32] (K must be 256). OHEAD: out head-major.
template<bool RESID, bool AHEAD, bool OHEAD>
__global__ __launch_bounds__(256, 2)
void gemm128(const u16* __restrict__ A, const u16* __restrict__ Wt,
             const float* __restrict__ bias, const float* __restrict__ resid,
             u16* __restrict__ out, int M, int N, int K) {
  __shared__ alignas(16) char sm[32768];
  char* sa = sm;
  char* sb = sm + 16384;
  const int tid = threadIdx.x;
  const int w = tid >> 6, lane = tid & 63;
  const int ln15 = lane & 15, gq = lane >> 4;
  const int wr = w >> 1, wc = w & 1;
  const int m0 = blockIdx.x * 128, n0 = blockIdx.y * 128;
  const char* Ab = (const char*)A;
  const char* Wb = (const char*)Wt;
  const int Kb = K * 2;  // row bytes

  float4v acc[4][4] = {};
  const int nk = K >> 6;
  for (int kk = 0; kk < nk; ++kk) {
    #pragma unroll
    for (int p = 0; p < 4; ++p) {
      int L = p * 4096 + w * 1024 + lane * 16;
      int row = L >> 7, colb = L & 127;
      int sw = colb ^ ((row & 7) << 4);
      if (AHEAD) {
        int b = kk * 128 + sw;  // logical byte within 512B row
        async16(Ab + (size_t)(b >> 6) * S64B + (size_t)(m0 + row) * 64 + (b & 63),
                sa + p * 4096 + w * 1024);
      } else {
        async16(Ab + (size_t)(m0 + row) * Kb + kk * 128 + sw, sa + p * 4096 + w * 1024);
      }
      async16(Wb + (size_t)(n0 + row) * Kb + kk * 128 + sw, sb + p * 4096 + w * 1024);
    }
    __syncthreads();
    #pragma unroll
    for (int ks = 0; ks < 2; ++ks) {
      short8v af[4], bfr[4];
      #pragma unroll
      for (int mf = 0; mf < 4; ++mf) {
        int r = wr * 64 + mf * 16 + ln15;
        af[mf] = *(const short8v*)(sa + r * 128 + ((ks * 64 + gq * 16) ^ ((r & 7) << 4)));
      }
      #pragma unroll
      for (int nf = 0; nf < 4; ++nf) {
        int r = wc * 64 + nf * 16 + ln15;
        bfr[nf] = *(const short8v*)(sb + r * 128 + ((ks * 64 + gq * 16) ^ ((r & 7) << 4)));
      }
      #pragma unroll
      for (int mf = 0; mf < 4; ++mf)
        #pragma unroll
        for (int nf = 0; nf < 4; ++nf)
          acc[mf][nf] = mfma32(af[mf], bfr[nf], acc[mf][nf]);
    }
    __syncthreads();
  }
  #pragma unroll
  for (int nf = 0; nf < 4; ++nf) {
    int col = n0 + wc * 64 + nf * 16 + ln15;
    float bb = bias[col];
    #pragma unroll
    for (int mf = 0; mf < 4; ++mf) {
      int rb = m0 + wr * 64 + mf * 16 + 4 * gq;
      #pragma unroll
      for (int j = 0; j < 4; ++j) {
        float v = acc[mf][nf][j] + bb;
        if (RESID) v += resid[(size_t)(rb + j) * N + col];
        if (OHEAD)
          out[(size_t)(col >> 5) * S32E + (size_t)(rb + j) * 32 + (col & 31)] = f2bf(v);
        else
          out[(size_t)(rb + j) * N + col] = f2bf(v);
      }
    }
  }
}

// ---------------- merged K/V projection GEMM (head-major outputs) ----------------
__global__ __launch_bounds__(256, 2)
void gemm_kv(const u16* __restrict__ A, const u16* __restrict__ Wt,
             const float* __restrict__ bk, const float* __restrict__ bv,
             u16* __restrict__ Kout, u16* __restrict__ Vout) {
  __shared__ alignas(16) char sm[32768];
  char* sa = sm;
  char* sb = sm + 16384;
  const int tid = threadIdx.x;
  const int w = tid >> 6, lane = tid & 63;
  const int ln15 = lane & 15, gq = lane >> 4;
  const int wr = w >> 1, wc = w & 1;
  const int m0 = blockIdx.x * 128, n0 = blockIdx.y * 128;
  const char* Ab = (const char*)A;
  const char* Wb = (const char*)Wt;

  float4v acc[4][4] = {};
  for (int kk = 0; kk < 4; ++kk) {
    #pragma unroll
    for (int p = 0; p < 4; ++p) {
      int L = p * 4096 + w * 1024 + lane * 16;
      int row = L >> 7, colb = L & 127;
      int sw = colb ^ ((row & 7) << 4);
      async16(Ab + (size_t)(m0 + row) * 512 + kk * 128 + sw, sa + p * 4096 + w * 1024);
      async16(Wb + (size_t)(n0 + row) * 512 + kk * 128 + sw, sb + p * 4096 + w * 1024);
    }
    __syncthreads();
    #pragma unroll
    for (int ks = 0; ks < 2; ++ks) {
      short8v af[4], bfr[4];
      #pragma unroll
      for (int mf = 0; mf < 4; ++mf) {
        int r = wr * 64 + mf * 16 + ln15;
        af[mf] = *(const short8v*)(sa + r * 128 + ((ks * 64 + gq * 16) ^ ((r & 7) << 4)));
      }
      #pragma unroll
      for (int nf = 0; nf < 4; ++nf) {
        int r = wc * 64 + nf * 16 + ln15;
        bfr[nf] = *(const short8v*)(sb + r * 128 + ((ks * 64 + gq * 16) ^ ((r & 7) << 4)));
      }
      #pragma unroll
      for (int mf = 0; mf < 4; ++mf)
        #pragma unroll
        for (int nf = 0; nf < 4; ++nf)
          acc[mf][nf] = mfma32(af[mf], bfr[nf], acc[mf][nf]);
    }
    __syncthreads();
  }
  #pragma unroll
  for (int nf = 0; nf < 4; ++nf) {
    int col = n0 + wc * 64 + nf * 16 + ln15;  // 0..511
    const bool isK = col < 256;
    const int c2 = col & 255;
    u16* outp = isK ? Kout : Vout;
    float bb = isK ? bk[c2] : bv[c2];
    const size_t hb = (size_t)(c2 >> 5) * S32E;
    const int d = c2 & 31;
    #pragma unroll
    for (int mf = 0; mf < 4; ++mf) {
      int rb = m0 + wr * 64 + mf * 16 + 4 * gq;
      #pragma unroll
      for (int j = 0; j < 4; ++j)
        outp[hb + (size_t)(rb + j) * 32 + d] = f2bf(acc[mf][nf][j] + bb);
    }
  }
}

// ---- Wo GEMM + residual + LN1 fused: x = LN1(q_in + ctx@Wo + bo), bf16 out ----
// ctx head-major [8][65536][32]; Wot [256][256]; resid = query f32 [65536][256].
// BM=128, BN=256 (grid.y=1 -> block owns full rows); 4 waves: wr=w>>1 rows 64,
// wc=w&1 cols 128. Epilogue: R2-proven cross-wave LN via LDS partials.
__global__ __launch_bounds__(256, 2)
void gemm_wo_ln(const u16* __restrict__ A, const u16* __restrict__ Wt,
                const float* __restrict__ bias, const float* __restrict__ resid,
                const float* __restrict__ lng, const float* __restrict__ lnb,
                u16* __restrict__ xout) {
  __shared__ alignas(16) char sa[16384];   // A tile [128][128B], XOR-swizzled
  __shared__ alignas(16) char sb[32768];   // B tile [256][128B], XOR-swizzled
  __shared__ float red[512];               // [128 rows][2 wc][2 {sum,sq}]
  const int tid = threadIdx.x;
  const int w = tid >> 6, lane = tid & 63;
  const int ln15 = lane & 15, gq = lane >> 4;
  const int wr = w >> 1, wc = w & 1;
  const int m0 = blockIdx.x * 128;
  const char* Ab = (const char*)A;
  const char* Wb = (const char*)Wt;

  float4v acc[4][8] = {};
  for (int kk = 0; kk < 4; ++kk) {
    // stage A [128][64k] (head-major source), 4 x 16B per thread
    #pragma unroll
    for (int p = 0; p < 4; ++p) {
      int L = p * 4096 + tid * 16;
      int row = L >> 7, colb = L & 127;
      int sw = colb ^ ((row & 7) << 4);
      int b = kk * 128 + sw;
      async16(Ab + (size_t)(b >> 6) * S64B + (size_t)(m0 + row) * 64 + (b & 63),
              sa + L);
    }
    // stage B [256][64k], 8 x 16B per thread
    #pragma unroll
    for (int p = 0; p < 8; ++p) {
      int L = p * 4096 + tid * 16;
      int row = L >> 7, colb = L & 127;
      int sw = colb ^ ((row & 7) << 4);
      async16(Wb + (size_t)row * 512 + kk * 128 + sw, sb + L);
    }
    __syncthreads();
    #pragma unroll
    for (int ks = 0; ks < 2; ++ks) {
      short8v af[4], bfr[8];
      #pragma unroll
      for (int mf = 0; mf < 4; ++mf) {
        int r = wr * 64 + mf * 16 + ln15;
        af[mf] = *(const short8v*)(sa + r * 128 + ((ks * 64 + gq * 16) ^ ((r & 7) << 4)));
      }
      #pragma unroll
      for (int nf = 0; nf < 8; ++nf) {
        int r = wc * 128 + nf * 16 + ln15;
        bfr[nf] = *(const short8v*)(sb + r * 128 + ((ks * 64 + gq * 16) ^ ((r & 7) << 4)));
      }
      #pragma unroll
      for (int mf = 0; mf < 4; ++mf)
        #pragma unroll
        for (int nf = 0; nf < 8; ++nf)
          acc[mf][nf] = mfma32(af[mf], bfr[nf], acc[mf][nf]);
    }
    __syncthreads();
  }

  // pass 1: v = acc + bias + resid (in place), per-row partial sums -> LDS
  #pragma unroll
  for (int mf = 0; mf < 4; ++mf)
    #pragma unroll
    for (int j = 0; j < 4; ++j) {
      int lr = wr * 64 + mf * 16 + 4 * gq + j;   // local row 0..127
      int r2 = m0 + lr;
      float sum = 0.f, sq = 0.f;
      #pragma unroll
      for (int nf = 0; nf < 8; ++nf) {
        int col = wc * 128 + nf * 16 + ln15;
        float v = acc[mf][nf][j] + bias[col] + resid[(size_t)r2 * 256 + col];
        acc[mf][nf][j] = v;
        sum += v;
        sq += v * v;
      }
      #pragma unroll
      for (int m = 1; m <= 8; m <<= 1) {
        sum += __shfl_xor(sum, m);
        sq += __shfl_xor(sq, m);
      }
      if (ln15 == 0) {
        red[lr * 4 + wc * 2] = sum;
        red[lr * 4 + wc * 2 + 1] = sq;
      }
    }
  __syncthreads();

  // pass 2: LN across 256 cols (combine wc partials), write bf16
  #pragma unroll
  for (int mf = 0; mf < 4; ++mf)
    #pragma unroll
    for (int j = 0; j < 4; ++j) {
      int lr = wr * 64 + mf * 16 + 4 * gq + j;
      int r2 = m0 + lr;
      float S = red[lr * 4] + red[lr * 4 + 2];
      float S2 = red[lr * 4 + 1] + red[lr * 4 + 3];
      float mu = S * (1.f / 256.f);
      float var = S2 * (1.f / 256.f) - mu * mu;
      float rstd = rsqrtf(var + 1e-5f);
      #pragma unroll
      for (int nf = 0; nf < 8; ++nf) {
        int col = wc * 128 + nf * 16 + ln15;
        float o = (acc[mf][nf][j] - mu) * rstd * lng[col] + lnb[col];
        xout[(size_t)r2 * 256 + col] = f2bf(o);
      }
    }
}

// ---------------- windowed attention v2: one block per (window, head) ----------------
__global__ __launch_bounds__(256, 2)
void attn_v2(const u16* __restrict__ Qg, const u16* __restrict__ Kg,
             const u16* __restrict__ Vg, u16* __restrict__ ctx) {
  __shared__ alignas(16) char ks[256 * 80];
  __shared__ alignas(16) char vs[256 * 80];
  const int bw = blockIdx.x;
  const int win = bw >> 3, head = bw & 7;
  const int tid = threadIdx.x;
  const int w = tid >> 6, lane = tid & 63;
  const int ln15 = lane & 15, gq = lane >> 4;
  const int tok0 = win << 8;
  const u16* Qh = Qg + head * S32E + (size_t)tok0 * 32;
  const u16* Kh = Kg + head * S32E + (size_t)tok0 * 32;
  const u16* Vh = Vg + head * S32E + (size_t)tok0 * 32;
  u16* Ch = ctx + head * S32E + (size_t)tok0 * 32;

  #pragma unroll
  for (int i = 0; i < 4; ++i) {
    int L = i * 4096 + tid * 16;
    int row = L >> 6, colb = L & 63;
    short8v kv0 = *(const short8v*)((const char*)Kh + L);
    short8v vv0 = *(const short8v*)((const char*)Vh + L);
    *(short8v*)(ks + row * 80 + colb) = kv0;
    *(short8v*)(vs + row * 80 + colb) = vv0;
  }
  __syncthreads();

  const float KSC = (float)(1.4426950408889634 / 5.656854249492381);  // log2e/sqrt(32)

  for (int pass = 0; pass < 2; ++pass) {
    const int q0 = w * 64 + pass * 32;

    short8v qf[2];
    #pragma unroll
    for (int qi = 0; qi < 2; ++qi)
      qf[qi] = *(const short8v*)(Qh + (size_t)(q0 + qi * 16 + ln15) * 32 + gq * 8);

    float4v s[16][2];
    #pragma unroll
    for (int kf = 0; kf < 16; ++kf) {
      short8v kfr = *(const short8v*)(ks + (16 * kf + ln15) * 80 + gq * 16);
      float4v z = {0.f, 0.f, 0.f, 0.f};
      s[kf][0] = mfma32(kfr, qf[0], z);
      s[kf][1] = mfma32(kfr, qf[1], z);
    }

    float rs[2];
    #pragma unroll
    for (int qi = 0; qi < 2; ++qi) {
      float mx = -1e30f;
      #pragma unroll
      for (int kf = 0; kf < 16; ++kf)
        #pragma unroll
        for (int j = 0; j < 4; ++j) mx = fmaxf(mx, s[kf][qi][j]);
      mx = fmaxf(mx, __shfl_xor(mx, 16));
      mx = fmaxf(mx, __shfl_xor(mx, 32));
      float mk = mx * KSC;
      float sum = 0.f;
      #pragma unroll
      for (int kf = 0; kf < 16; ++kf)
        #pragma unroll
        for (int j = 0; j < 4; ++j) {
          float p = exp2f(fmaf(s[kf][qi][j], KSC, -mk));
          s[kf][qi][j] = p;
          sum += p;
        }
      sum += __shfl_xor(sum, 16);
      sum += __shfl_xor(sum, 32);
      rs[qi] = 1.0f / sum;
    }

    float4v cacc[2][2] = {};  // [df][qi]
    #pragma unroll
    for (int kss = 0; kss < 16; ++kss) {
      short4v pb[2];
      pb[0] = cvt4(s[kss][0]);
      pb[1] = cvt4(s[kss][1]);
      #pragma unroll
      for (int df = 0; df < 2; ++df) {
        const char* vb = vs + (size_t)(16 * kss + 4 * gq) * 80 + (df * 16 + ln15) * 2;
        short4v va;
        va[0] = *(const short*)(vb);
        va[1] = *(const short*)(vb + 80);
        va[2] = *(const short*)(vb + 160);
        va[3] = *(const short*)(vb + 240);
        cacc[df][0] = mfma16(va, pb[0], cacc[df][0]);
        cacc[df][1] = mfma16(va, pb[1], cacc[df][1]);
      }
    }

    #pragma unroll
    for (int qi = 0; qi < 2; ++qi)
      #pragma unroll
      for (int df = 0; df < 2; ++df) {
        short4v o;
        #pragma unroll
        for (int j = 0; j < 4; ++j) o[j] = (short)f2bf(cacc[df][qi][j] * rs[qi]);
        *(short4v*)(Ch + (size_t)(q0 + qi * 16 + ln15) * 32 + df * 16 + 4 * gq) = o;
      }
  }
}

// ---------------- fused FFN v6 + residual + LN2 (R8-proven, verbatim) ----------------
__global__ __launch_bounds__(512, 2)
void ffn_v6(const u16* __restrict__ X, const u16* __restrict__ W1t,
            const u16* __restrict__ W2tp, const float* __restrict__ b1,
            const float* __restrict__ b2, const float* __restrict__ g2,
            const float* __restrict__ be2, float* __restrict__ out) {
  __shared__ alignas(16) char w1c[2][16384];   // [32 f][512B k], XOR-swizzled
  __shared__ alignas(16) char w2c[2][20480];   // [256 n][80B] (64B data + 16 pad)
  __shared__ alignas(16) float b1s[1024];
  const int tid = threadIdx.x;  // 0..511
  const int w = tid >> 6, lane = tid & 63;
  const int ln15 = lane & 15, gq = lane >> 4;
  const int m0 = blockIdx.x * 256;
  const int wrow0 = m0 + w * 32;

  b1s[tid] = b1[tid];
  b1s[tid + 512] = b1[tid + 512];

  short8v xr[2][8];
  #pragma unroll
  for (int ct = 0; ct < 2; ++ct)
    #pragma unroll
    for (int kc = 0; kc < 8; ++kc)
      xr[ct][kc] = *(const short8v*)(X + (size_t)(wrow0 + ct * 16 + ln15) * 256 + kc * 32 + gq * 8);

  float4v ff[2][16] = {};
  short8v w2r[2];

  const char* W1b = (const char*)W1t;
  const char* W2b = (const char*)W2tp;

  #define STAGE_W1(buf, c)                                                     \
    {                                                                          \
      _Pragma("unroll")                                                        \
      for (int p = 0; p < 2; ++p) {                                            \
        int L = p * 8192 + tid * 16;                                           \
        int r = L >> 9, colb = L & 511;                                        \
        async16(W1b + (size_t)((c) * 32 + r) * 512 + (colb ^ ((r & 7) << 4)),  \
                w1c[buf] + L);                                                 \
      }                                                                        \
    }
  #define LOAD_W2(c)                                                           \
    {                                                                          \
      _Pragma("unroll")                                                        \
      for (int p = 0; p < 2; ++p) {                                            \
        int idx = p * 8192 + tid * 16;                                         \
        int n = idx >> 6, off = idx & 63;                                      \
        w2r[p] = *(const short8v*)(W2b + (size_t)n * 2048 + (c) * 64 + off);   \
      }                                                                        \
    }
  #define WRITE_W2(buf)                                                        \
    {                                                                          \
      _Pragma("unroll")                                                        \
      for (int p = 0; p < 2; ++p) {                                            \
        int idx = p * 8192 + tid * 16;                                         \
        int n = idx >> 6, off = idx & 63;                                      \
        *(short8v*)(w2c[buf] + n * 80 + off) = w2r[p];                         \
      }                                                                        \
    }

  STAGE_W1(0, 0);
  LOAD_W2(0);
  WRITE_W2(0);
  __syncthreads();

  #pragma unroll 2
  for (int c = 0; c < 32; ++c) {
    const int buf = c & 1;
    if (c < 31) {
      STAGE_W1(buf ^ 1, c + 1);
      LOAD_W2(c + 1);
    }

    float4v g1[2][2] = {};
    #pragma unroll
    for (int kc = 0; kc < 8; ++kc) {
      #pragma unroll
      for (int ft = 0; ft < 2; ++ft) {
        int r = ft * 16 + ln15;
        short8v a = *(const short8v*)(w1c[buf] + r * 512 +
                                      ((kc * 64 + gq * 16) ^ ((r & 7) << 4)));
        g1[0][ft] = mfma32(a, xr[0][kc], g1[0][ft]);
        g1[1][ft] = mfma32(a, xr[1][kc], g1[1][ft]);
      }
    }
    short8v pa8[2];
    #pragma unroll
    for (int ft = 0; ft < 2; ++ft) {
      float4v bv4 = *(const float4v*)(b1s + c * 32 + ft * 16 + 4 * gq);
      #pragma unroll
      for (int ct = 0; ct < 2; ++ct)
        #pragma unroll
        for (int j = 0; j < 4; ++j) {
          float v = g1[ct][ft][j] + bv4[j];
          v = v > 0.f ? v : 0.f;
          pa8[ct][ft * 4 + j] = (short)f2bf(v);
        }
    }
    #pragma unroll
    for (int nt = 0; nt < 16; ++nt) {
      short8v wb = *(const short8v*)(w2c[buf] + (nt * 16 + ln15) * 80 + gq * 16);
      ff[0][nt] = mfma32(pa8[0], wb, ff[0][nt]);
      ff[1][nt] = mfma32(pa8[1], wb, ff[1][nt]);
    }

    if (c < 31) WRITE_W2(buf ^ 1);
    __syncthreads();
  }

  #pragma unroll
  for (int ct = 0; ct < 2; ++ct)
    #pragma unroll
    for (int j = 0; j < 4; ++j) {
      int r2 = wrow0 + ct * 16 + 4 * gq + j;
      float sum = 0.f, sq = 0.f;
      float vv[16];
      #pragma unroll
      for (int nt = 0; nt < 16; ++nt) {
        int col = nt * 16 + ln15;
        float xv = bf2f(X[(size_t)r2 * 256 + col]);
        float v = ff[ct][nt][j] + b2[col] + xv;
        vv[nt] = v;
        sum += v;
        sq += v * v;
      }
      #pragma unroll
      for (int m = 1; m <= 8; m <<= 1) {
        sum += __shfl_xor(sum, m);
        sq += __shfl_xor(sq, m);
      }
      float mu = sum * (1.f / 256.f);
      float var = sq * (1.f / 256.f) - mu * mu;
      float rstd = rsqrtf(var + 1e-5f);
      #pragma unroll
      for (int nt = 0; nt < 16; ++nt) {
        int col = nt * 16 + ln15;
        out[(size_t)r2 * 256 + col] = (vv[nt] - mu) * rstd * g2[col] + be2[col];
      }
    }
  #undef STAGE_W1
  #undef LOAD_W2
  #undef WRITE_W2
}

extern "C" void kernel_launch(void* const* d_in, const int* in_sizes, int n_in,
                              void* d_out, int out_size, void* d_ws, size_t ws_size,
                              hipStream_t stream) {
  (void)in_sizes; (void)n_in; (void)out_size;
  const float* query = (const float*)d_in[0];
  const float* kv    = (const float*)d_in[1];
  const float* Wqm = (const float*)d_in[2];  const float* bq = (const float*)d_in[3];
  const float* Wkm = (const float*)d_in[4];  const float* bk = (const float*)d_in[5];
  const float* Wvm = (const float*)d_in[6];  const float* bv = (const float*)d_in[7];
  const float* Wom = (const float*)d_in[8];  const float* bo = (const float*)d_in[9];
  const float* ln1g = (const float*)d_in[10]; const float* ln1b = (const float*)d_in[11];
  const float* W1m = (const float*)d_in[12]; const float* b1 = (const float*)d_in[13];
  const float* W2m = (const float*)d_in[14]; const float* b2 = (const float*)d_in[15];
  const float* ln2g = (const float*)d_in[16]; const float* ln2b = (const float*)d_in[17];
  float* out = (float*)d_out;

  char* ws = (char*)d_ws;
  const size_t MB = 1ull << 20;
  if (ws_size < 130 * MB) return;

  // lifetime-aliased layout (all bf16); Q/K/V/ctx are head-major [8][65536][32]
  u16* qbf  = (u16*)(ws);            // input q bf16; dead after Q-proj
  u16* kvbf = (u16*)(ws + 32 * MB);  // input kv bf16; dead after V-proj
  u16* Vw   = (u16*)(ws);            // aliases qbf
  u16* ctxw = (u16*)(ws + 32 * MB);  // aliases kvbf
  u16* Qw   = (u16*)(ws + 64 * MB);  // dead after attn
  u16* xw   = (u16*)(ws + 64 * MB);  // aliases Qw
  u16* Kw   = (u16*)(ws + 96 * MB);
  char* wb = ws + 128 * MB;
  u16* Wqt = (u16*)(wb);
  u16* Wkt = (u16*)(wb + 131072);
  u16* Wvt = (u16*)(wb + 262144);
  u16* Wot = (u16*)(wb + 393216);
  u16* W1t = (u16*)(wb + 524288);
  u16* W2t = (u16*)(wb + 1048576);

  cvt_in<<<dim3(8192, 2), 256, 0, stream>>>(query, kv, qbf, kvbf);
  cvt_wT<<<dim3(64, 6), 256, 0, stream>>>(Wqm, Wkm, Wvm, Wom, W1m, W2m,
                                          Wqt, Wkt, Wvt, Wot, W1t, W2t);
  gemm128<false, false, true><<<dim3(512, 2), 256, 0, stream>>>(
      qbf, Wqt, bq, nullptr, Qw, 65536, 256, 256);
  gemm_kv<<<dim3(512, 4), 256, 0, stream>>>(kvbf, Wkt, bk, bv, Kw, Vw);
  attn_v2<<<dim3(2048), 256, 0, stream>>>(Qw, Kw, Vw, ctxw);
  gemm_wo_ln<<<dim3(512), 256, 0, stream>>>(ctxw, Wot, bo, query, ln1g, ln1b, xw);
  ffn_v6<<<dim3(256), 512, 0, stream>>>(xw, W1t, W2t, b1, b2, ln2g, ln2b, out);
}

// Round 12
// 280.597 us; speedup vs baseline: 1.4449x; 1.0813x over previous
//
#include <hip/hip_runtime.h>

#define DEV __device__ __forceinline__

typedef short short4v __attribute__((ext_vector_type(4)));
typedef short short8v __attribute__((ext_vector_type(8)));
typedef float float4v __attribute__((ext_vector_type(4)));
typedef unsigned short u16;

#define S32E ((size_t)65536 * 32)   // head stride, elements (u16)
#define S64B ((size_t)65536 * 64)   // head stride, bytes

DEV unsigned short f2bf(float f) {
  unsigned u = __builtin_bit_cast(unsigned, f);
  u += 0x7fffu + ((u >> 16) & 1u);
  return (unsigned short)(u >> 16);
}
DEV float bf2f(unsigned short h) {
  unsigned u = ((unsigned)h) << 16;
  return __builtin_bit_cast(float, u);
}
DEV float4v mfma32(short8v a, short8v b, float4v c) {
  return __builtin_amdgcn_mfma_f32_16x16x32_bf16(a, b, c, 0, 0, 0);
}
DEV float4v mfma16(short4v a, short4v b, float4v c) {
  return __builtin_amdgcn_mfma_f32_16x16x16bf16_1k(a, b, c, 0, 0, 0);
}
DEV void async16(const void* g, void* l) {
  __builtin_amdgcn_global_load_lds(
      (const __attribute__((address_space(1))) unsigned*)g,
      (__attribute__((address_space(3))) unsigned*)l, 16, 0, 0);
}
DEV short4v cvt4(float4v v) {
  short4v r;
  r[0] = (short)f2bf(v[0]); r[1] = (short)f2bf(v[1]);
  r[2] = (short)f2bf(v[2]); r[3] = (short)f2bf(v[3]);
  return r;
}
DEV short8v cvt8(float4v a, float4v b) {
  short8v o;
  o[0] = (short)f2bf(a[0]); o[1] = (short)f2bf(a[1]);
  o[2] = (short)f2bf(a[2]); o[3] = (short)f2bf(a[3]);
  o[4] = (short)f2bf(b[0]); o[5] = (short)f2bf(b[1]);
  o[6] = (short)f2bf(b[2]); o[7] = (short)f2bf(b[3]);
  return o;
}

// ------------- weight convert + transpose (LDS-tiled, coalesced) -------------
__global__ __launch_bounds__(256)
void cvt_wT(const float* Wq, const float* Wk, const float* Wv, const float* Wo,
            const float* W1, const float* W2,
            u16* Wqt, u16* Wkt, u16* Wvt, u16* Wot, u16* W1t, u16* W2t) {
  __shared__ float ld[64 * 69];
  const float* src; u16* dst; int R, C; bool permk = false;
  switch (blockIdx.y) {
    case 0: src = Wq; dst = Wqt; R = 256;  C = 256;  break;
    case 1: src = Wk; dst = Wkt; R = 256;  C = 256;  break;
    case 2: src = Wv; dst = Wvt; R = 256;  C = 256;  break;
    case 3: src = Wo; dst = Wot; R = 256;  C = 256;  break;
    case 4: src = W1; dst = W1t; R = 256;  C = 1024; break;
    default: src = W2; dst = W2t; R = 1024; C = 256; permk = true; break;
  }
  const int ntile = (R >> 6) * (C >> 6);
  if ((int)blockIdx.x >= ntile) return;
  const int tf = blockIdx.x % (R >> 6);
  const int tn = blockIdx.x / (R >> 6);
  const int r0 = tf << 6, c0 = tn << 6;
  const int tid = threadIdx.x;
  {
    int lr = tid >> 4, lc = (tid & 15) << 2;
    #pragma unroll
    for (int ps = 0; ps < 4; ++ps) {
      int r = ps * 16 + lr;
      float4v v = *(const float4v*)(src + (size_t)(r0 + r) * C + c0 + lc);
      #pragma unroll
      for (int e = 0; e < 4; ++e) ld[r * 69 + lc + e] = v[e];
    }
  }
  __syncthreads();
  {
    int p8 = (tid & 7) << 3;
    #pragma unroll
    for (int ps = 0; ps < 2; ++ps) {
      int n = ps * 32 + (tid >> 3);
      short8v o;
      #pragma unroll
      for (int e = 0; e < 8; ++e) {
        int p = p8 + e;
        int fl = p;
        if (permk) {
          int m = p & 31;
          fl = (p & 32) + 16 * ((m >> 2) & 1) + 4 * (m >> 3) + (m & 3);
        }
        o[e] = (short)f2bf(ld[fl * 69 + n]);
      }
      *(short8v*)(dst + (size_t)(c0 + n) * R + r0 + p8) = o;
    }
  }
}

// ---------------- Q projection GEMM: out = A_f32 @ Wt^T + bias, head-major out ----
// A: [M][256] f32 (converted to bf16 during reg-staged A tile); Wt: [256][256] bf16.
__global__ __launch_bounds__(256, 2)
void gemm_q(const float* __restrict__ A, const u16* __restrict__ Wt,
            const float* __restrict__ bias, u16* __restrict__ out) {
  __shared__ alignas(16) char sm[32768];
  char* sa = sm;
  char* sb = sm + 16384;
  const int tid = threadIdx.x;
  const int w = tid >> 6, lane = tid & 63;
  const int ln15 = lane & 15, gq = lane >> 4;
  const int wr = w >> 1, wc = w & 1;
  const int m0 = blockIdx.x * 128, n0 = blockIdx.y * 128;
  const char* Wb = (const char*)Wt;

  float4v acc[4][4] = {};
  for (int kk = 0; kk < 4; ++kk) {
    // A: reg-stage f32 -> bf16 -> swizzled ds_write (linear coalesced source)
    #pragma unroll
    for (int p = 0; p < 4; ++p) {
      int L = p * 4096 + w * 1024 + lane * 16;
      int row = L >> 7, colb = L & 127;
      const float* src = A + (size_t)(m0 + row) * 256 + kk * 64 + (colb >> 1);
      float4v f0 = *(const float4v*)(src);
      float4v f1 = *(const float4v*)(src + 4);
      *(short8v*)(sa + row * 128 + (colb ^ ((row & 7) << 4))) = cvt8(f0, f1);
    }
    // B: global_load_lds with pre-swizzled source
    #pragma unroll
    for (int p = 0; p < 4; ++p) {
      int L = p * 4096 + w * 1024 + lane * 16;
      int row = L >> 7, colb = L & 127;
      int sw = colb ^ ((row & 7) << 4);
      async16(Wb + (size_t)(n0 + row) * 512 + kk * 128 + sw, sb + p * 4096 + w * 1024);
    }
    __syncthreads();
    #pragma unroll
    for (int ks = 0; ks < 2; ++ks) {
      short8v af[4], bfr[4];
      #pragma unroll
      for (int mf = 0; mf < 4; ++mf) {
        int r = wr * 64 + mf * 16 + ln15;
        af[mf] = *(const short8v*)(sa + r * 128 + ((ks * 64 + gq * 16) ^ ((r & 7) << 4)));
      }
      #pragma unroll
      for (int nf = 0; nf < 4; ++nf) {
        int r = wc * 64 + nf * 16 + ln15;
        bfr[nf] = *(const short8v*)(sb + r * 128 + ((ks * 64 + gq * 16) ^ ((r & 7) << 4)));
      }
      #pragma unroll
      for (int mf = 0; mf < 4; ++mf)
        #pragma unroll
        for (int nf = 0; nf < 4; ++nf)
          acc[mf][nf] = mfma32(af[mf], bfr[nf], acc[mf][nf]);
    }
    __syncthreads();
  }
  #pragma unroll
  for (int nf = 0; nf < 4; ++nf) {
    int col = n0 + wc * 64 + nf * 16 + ln15;
    float bb = bias[col];
    #pragma unroll
    for (int mf = 0; mf < 4; ++mf) {
      int rb = m0 + wr * 64 + mf * 16 + 4 * gq;
      #pragma unroll
      for (int j = 0; j < 4; ++j) {
        float v = acc[mf][nf][j] + bb;
        out[(size_t)(col >> 5) * S32E + (size_t)(rb + j) * 32 + (col & 31)] = f2bf(v);
      }
    }
  }
}

// ---------------- merged K/V projection GEMM (f32 A, head-major outputs) ----------------
__global__ __launch_bounds__(256, 2)
void gemm_kv(const float* __restrict__ A, const u16* __restrict__ Wt,
             const float* __restrict__ bk, const float* __restrict__ bv,
             u16* __restrict__ Kout, u16* __restrict__ Vout) {
  __shared__ alignas(16) char sm[32768];
  char* sa = sm;
  char* sb = sm + 16384;
  const int tid = threadIdx.x;
  const int w = tid >> 6, lane = tid & 63;
  const int ln15 = lane & 15, gq = lane >> 4;
  const int wr = w >> 1, wc = w & 1;
  const int m0 = blockIdx.x * 128, n0 = blockIdx.y * 128;
  const char* Wb = (const char*)Wt;

  float4v acc[4][4] = {};
  for (int kk = 0; kk < 4; ++kk) {
    #pragma unroll
    for (int p = 0; p < 4; ++p) {
      int L = p * 4096 + w * 1024 + lane * 16;
      int row = L >> 7, colb = L & 127;
      const float* src = A + (size_t)(m0 + row) * 256 + kk * 64 + (colb >> 1);
      float4v f0 = *(const float4v*)(src);
      float4v f1 = *(const float4v*)(src + 4);
      *(short8v*)(sa + row * 128 + (colb ^ ((row & 7) << 4))) = cvt8(f0, f1);
    }
    #pragma unroll
    for (int p = 0; p < 4; ++p) {
      int L = p * 4096 + w * 1024 + lane * 16;
      int row = L >> 7, colb = L & 127;
      int sw = colb ^ ((row & 7) << 4);
      async16(Wb + (size_t)(n0 + row) * 512 + kk * 128 + sw, sb + p * 4096 + w * 1024);
    }
    __syncthreads();
    #pragma unroll
    for (int ks = 0; ks < 2; ++ks) {
      short8v af[4], bfr[4];
      #pragma unroll
      for (int mf = 0; mf < 4; ++mf) {
        int r = wr * 64 + mf * 16 + ln15;
        af[mf] = *(const short8v*)(sa + r * 128 + ((ks * 64 + gq * 16) ^ ((r & 7) << 4)));
      }
      #pragma unroll
      for (int nf = 0; nf < 4; ++nf) {
        int r = wc * 64 + nf * 16 + ln15;
        bfr[nf] = *(const short8v*)(sb + r * 128 + ((ks * 64 + gq * 16) ^ ((r & 7) << 4)));
      }
      #pragma unroll
      for (int mf = 0; mf < 4; ++mf)
        #pragma unroll
        for (int nf = 0; nf < 4; ++nf)
          acc[mf][nf] = mfma32(af[mf], bfr[nf], acc[mf][nf]);
    }
    __syncthreads();
  }
  #pragma unroll
  for (int nf = 0; nf < 4; ++nf) {
    int col = n0 + wc * 64 + nf * 16 + ln15;  // 0..511
    const bool isK = col < 256;
    const int c2 = col & 255;
    u16* outp = isK ? Kout : Vout;
    float bb = isK ? bk[c2] : bv[c2];
    const size_t hb = (size_t)(c2 >> 5) * S32E;
    const int d = c2 & 31;
    #pragma unroll
    for (int mf = 0; mf < 4; ++mf) {
      int rb = m0 + wr * 64 + mf * 16 + 4 * gq;
      #pragma unroll
      for (int j = 0; j < 4; ++j)
        outp[hb + (size_t)(rb + j) * 32 + d] = f2bf(acc[mf][nf][j] + bb);
    }
  }
}

// ---- Wo GEMM + residual + LN1 fused: x = LN1(q_in + ctx@Wo + bo), bf16 out ----
__global__ __launch_bounds__(256, 2)
void gemm_wo_ln(const u16* __restrict__ A, const u16* __restrict__ Wt,
                const float* __restrict__ bias, const float* __restrict__ resid,
                const float* __restrict__ lng, const float* __restrict__ lnb,
                u16* __restrict__ xout) {
  __shared__ alignas(16) char sa[16384];   // A tile [128][128B], XOR-swizzled
  __shared__ alignas(16) char sb[32768];   // B tile [256][128B], XOR-swizzled
  __shared__ float red[512];               // [128 rows][2 wc][2 {sum,sq}]
  const int tid = threadIdx.x;
  const int w = tid >> 6, lane = tid & 63;
  const int ln15 = lane & 15, gq = lane >> 4;
  const int wr = w >> 1, wc = w & 1;
  const int m0 = blockIdx.x * 128;
  const char* Ab = (const char*)A;
  const char* Wb = (const char*)Wt;

  float4v acc[4][8] = {};
  for (int kk = 0; kk < 4; ++kk) {
    #pragma unroll
    for (int p = 0; p < 4; ++p) {
      int L = p * 4096 + tid * 16;
      int row = L >> 7, colb = L & 127;
      int sw = colb ^ ((row & 7) << 4);
      int b = kk * 128 + sw;
      async16(Ab + (size_t)(b >> 6) * S64B + (size_t)(m0 + row) * 64 + (b & 63),
              sa + L);
    }
    #pragma unroll
    for (int p = 0; p < 8; ++p) {
      int L = p * 4096 + tid * 16;
      int row = L >> 7, colb = L & 127;
      int sw = colb ^ ((row & 7) << 4);
      async16(Wb + (size_t)row * 512 + kk * 128 + sw, sb + L);
    }
    __syncthreads();
    #pragma unroll
    for (int ks = 0; ks < 2; ++ks) {
      short8v af[4], bfr[8];
      #pragma unroll
      for (int mf = 0; mf < 4; ++mf) {
        int r = wr * 64 + mf * 16 + ln15;
        af[mf] = *(const short8v*)(sa + r * 128 + ((ks * 64 + gq * 16) ^ ((r & 7) << 4)));
      }
      #pragma unroll
      for (int nf = 0; nf < 8; ++nf) {
        int r = wc * 128 + nf * 16 + ln15;
        bfr[nf] = *(const short8v*)(sb + r * 128 + ((ks * 64 + gq * 16) ^ ((r & 7) << 4)));
      }
      #pragma unroll
      for (int mf = 0; mf < 4; ++mf)
        #pragma unroll
        for (int nf = 0; nf < 8; ++nf)
          acc[mf][nf] = mfma32(af[mf], bfr[nf], acc[mf][nf]);
    }
    __syncthreads();
  }

  #pragma unroll
  for (int mf = 0; mf < 4; ++mf)
    #pragma unroll
    for (int j = 0; j < 4; ++j) {
      int lr = wr * 64 + mf * 16 + 4 * gq + j;   // local row 0..127
      int r2 = m0 + lr;
      float sum = 0.f, sq = 0.f;
      #pragma unroll
      for (int nf = 0; nf < 8; ++nf) {
        int col = wc * 128 + nf * 16 + ln15;
        float v = acc[mf][nf][j] + bias[col] + resid[(size_t)r2 * 256 + col];
        acc[mf][nf][j] = v;
        sum += v;
        sq += v * v;
      }
      #pragma unroll
      for (int m = 1; m <= 8; m <<= 1) {
        sum += __shfl_xor(sum, m);
        sq += __shfl_xor(sq, m);
      }
      if (ln15 == 0) {
        red[lr * 4 + wc * 2] = sum;
        red[lr * 4 + wc * 2 + 1] = sq;
      }
    }
  __syncthreads();

  #pragma unroll
  for (int mf = 0; mf < 4; ++mf)
    #pragma unroll
    for (int j = 0; j < 4; ++j) {
      int lr = wr * 64 + mf * 16 + 4 * gq + j;
      int r2 = m0 + lr;
      float S = red[lr * 4] + red[lr * 4 + 2];
      float S2 = red[lr * 4 + 1] + red[lr * 4 + 3];
      float mu = S * (1.f / 256.f);
      float var = S2 * (1.f / 256.f) - mu * mu;
      float rstd = rsqrtf(var + 1e-5f);
      #pragma unroll
      for (int nf = 0; nf < 8; ++nf) {
        int col = wc * 128 + nf * 16 + ln15;
        float o = (acc[mf][nf][j] - mu) * rstd * lng[col] + lnb[col];
        xout[(size_t)r2 * 256 + col] = f2bf(o);
      }
    }
}

// ---------------- windowed attention v2: one block per (window, head) ----------------
__global__ __launch_bounds__(256, 2)
void attn_v2(const u16* __restrict__ Qg, const u16* __restrict__ Kg,
             const u16* __restrict__ Vg, u16* __restrict__ ctx) {
  __shared__ alignas(16) char ks[256 * 80];
  __shared__ alignas(16) char vs[256 * 80];
  const int bw = blockIdx.x;
  const int win = bw >> 3, head = bw & 7;
  const int tid = threadIdx.x;
  const int w = tid >> 6, lane = tid & 63;
  const int ln15 = lane & 15, gq = lane >> 4;
  const int tok0 = win << 8;
  const u16* Qh = Qg + head * S32E + (size_t)tok0 * 32;
  const u16* Kh = Kg + head * S32E + (size_t)tok0 * 32;
  const u16* Vh = Vg + head * S32E + (size_t)tok0 * 32;
  u16* Ch = ctx + head * S32E + (size_t)tok0 * 32;

  #pragma unroll
  for (int i = 0; i < 4; ++i) {
    int L = i * 4096 + tid * 16;
    int row = L >> 6, colb = L & 63;
    short8v kv0 = *(const short8v*)((const char*)Kh + L);
    short8v vv0 = *(const short8v*)((const char*)Vh + L);
    *(short8v*)(ks + row * 80 + colb) = kv0;
    *(short8v*)(vs + row * 80 + colb) = vv0;
  }
  __syncthreads();

  const float KSC = (float)(1.4426950408889634 / 5.656854249492381);  // log2e/sqrt(32)

  for (int pass = 0; pass < 2; ++pass) {
    const int q0 = w * 64 + pass * 32;

    short8v qf[2];
    #pragma unroll
    for (int qi = 0; qi < 2; ++qi)
      qf[qi] = *(const short8v*)(Qh + (size_t)(q0 + qi * 16 + ln15) * 32 + gq * 8);

    float4v s[16][2];
    #pragma unroll
    for (int kf = 0; kf < 16; ++kf) {
      short8v kfr = *(const short8v*)(ks + (16 * kf + ln15) * 80 + gq * 16);
      float4v z = {0.f, 0.f, 0.f, 0.f};
      s[kf][0] = mfma32(kfr, qf[0], z);
      s[kf][1] = mfma32(kfr, qf[1], z);
    }

    float rs[2];
    #pragma unroll
    for (int qi = 0; qi < 2; ++qi) {
      float mx = -1e30f;
      #pragma unroll
      for (int kf = 0; kf < 16; ++kf)
        #pragma unroll
        for (int j = 0; j < 4; ++j) mx = fmaxf(mx, s[kf][qi][j]);
      mx = fmaxf(mx, __shfl_xor(mx, 16));
      mx = fmaxf(mx, __shfl_xor(mx, 32));
      float mk = mx * KSC;
      float sum = 0.f;
      #pragma unroll
      for (int kf = 0; kf < 16; ++kf)
        #pragma unroll
        for (int j = 0; j < 4; ++j) {
          float p = exp2f(fmaf(s[kf][qi][j], KSC, -mk));
          s[kf][qi][j] = p;
          sum += p;
        }
      sum += __shfl_xor(sum, 16);
      sum += __shfl_xor(sum, 32);
      rs[qi] = 1.0f / sum;
    }

    float4v cacc[2][2] = {};  // [df][qi]
    #pragma unroll
    for (int kss = 0; kss < 16; ++kss) {
      short4v pb[2];
      pb[0] = cvt4(s[kss][0]);
      pb[1] = cvt4(s[kss][1]);
      #pragma unroll
      for (int df = 0; df < 2; ++df) {
        const char* vb = vs + (size_t)(16 * kss + 4 * gq) * 80 + (df * 16 + ln15) * 2;
        short4v va;
        va[0] = *(const short*)(vb);
        va[1] = *(const short*)(vb + 80);
        va[2] = *(const short*)(vb + 160);
        va[3] = *(const short*)(vb + 240);
        cacc[df][0] = mfma16(va, pb[0], cacc[df][0]);
        cacc[df][1] = mfma16(va, pb[1], cacc[df][1]);
      }
    }

    #pragma unroll
    for (int qi = 0; qi < 2; ++qi)
      #pragma unroll
      for (int df = 0; df < 2; ++df) {
        short4v o;
        #pragma unroll
        for (int j = 0; j < 4; ++j) o[j] = (short)f2bf(cacc[df][qi][j] * rs[qi]);
        *(short4v*)(Ch + (size_t)(q0 + qi * 16 + ln15) * 32 + df * 16 + 4 * gq) = o;
      }
  }
}

// ---------------- fused FFN v6 + residual + LN2 (R8/R10-proven, verbatim) ----------------
__global__ __launch_bounds__(512, 2)
void ffn_v6(const u16* __restrict__ X, const u16* __restrict__ W1t,
            const u16* __restrict__ W2tp, const float* __restrict__ b1,
            const float* __restrict__ b2, const float* __restrict__ g2,
            const float* __restrict__ be2, float* __restrict__ out) {
  __shared__ alignas(16) char w1c[2][16384];   // [32 f][512B k], XOR-swizzled
  __shared__ alignas(16) char w2c[2][20480];   // [256 n][80B] (64B data + 16 pad)
  __shared__ alignas(16) float b1s[1024];
  const int tid = threadIdx.x;  // 0..511
  const int w = tid >> 6, lane = tid & 63;
  const int ln15 = lane & 15, gq = lane >> 4;
  const int m0 = blockIdx.x * 256;
  const int wrow0 = m0 + w * 32;

  b1s[tid] = b1[tid];
  b1s[tid + 512] = b1[tid + 512];

  short8v xr[2][8];
  #pragma unroll
  for (int ct = 0; ct < 2; ++ct)
    #pragma unroll
    for (int kc = 0; kc < 8; ++kc)
      xr[ct][kc] = *(const short8v*)(X + (size_t)(wrow0 + ct * 16 + ln15) * 256 + kc * 32 + gq * 8);

  float4v ff[2][16] = {};
  short8v w2r[2];

  const char* W1b = (const char*)W1t;
  const char* W2b = (const char*)W2tp;

  #define STAGE_W1(buf, c)                                                     \
    {                                                                          \
      _Pragma("unroll")                                                        \
      for (int p = 0; p < 2; ++p) {                                            \
        int L = p * 8192 + tid * 16;                                           \
        int r = L >> 9, colb = L & 511;                                        \
        async16(W1b + (size_t)((c) * 32 + r) * 512 + (colb ^ ((r & 7) << 4)),  \
                w1c[buf] + L);                                                 \
      }                                                                        \
    }
  #define LOAD_W2(c)                                                           \
    {                                                                          \
      _Pragma("unroll")                                                        \
      for (int p = 0; p < 2; ++p) {                                            \
        int idx = p * 8192 + tid * 16;                                         \
        int n = idx >> 6, off = idx & 63;                                      \
        w2r[p] = *(const short8v*)(W2b + (size_t)n * 2048 + (c) * 64 + off);   \
      }                                                                        \
    }
  #define WRITE_W2(buf)                                                        \
    {                                                                          \
      _Pragma("unroll")                                                        \
      for (int p = 0; p < 2; ++p) {                                            \
        int idx = p * 8192 + tid * 16;                                         \
        int n = idx >> 6, off = idx & 63;                                      \
        *(short8v*)(w2c[buf] + n * 80 + off) = w2r[p];                         \
      }                                                                        \
    }

  STAGE_W1(0, 0);
  LOAD_W2(0);
  WRITE_W2(0);
  __syncthreads();

  #pragma unroll 2
  for (int c = 0; c < 32; ++c) {
    const int buf = c & 1;
    if (c < 31) {
      STAGE_W1(buf ^ 1, c + 1);
      LOAD_W2(c + 1);
    }

    float4v g1[2][2] = {};
    #pragma unroll
    for (int kc = 0; kc < 8; ++kc) {
      #pragma unroll
      for (int ft = 0; ft < 2; ++ft) {
        int r = ft * 16 + ln15;
        short8v a = *(const short8v*)(w1c[buf] + r * 512 +
                                      ((kc * 64 + gq * 16) ^ ((r & 7) << 4)));
        g1[0][ft] = mfma32(a, xr[0][kc], g1[0][ft]);
        g1[1][ft] = mfma32(a, xr[1][kc], g1[1][ft]);
      }
    }
    short8v pa8[2];
    #pragma unroll
    for (int ft = 0; ft < 2; ++ft) {
      float4v bv4 = *(const float4v*)(b1s + c * 32 + ft * 16 + 4 * gq);
      #pragma unroll
      for (int ct = 0; ct < 2; ++ct)
        #pragma unroll
        for (int j = 0; j < 4; ++j) {
          float v = g1[ct][ft][j] + bv4[j];
          v = v > 0.f ? v : 0.f;
          pa8[ct][ft * 4 + j] = (short)f2bf(v);
        }
    }
    #pragma unroll
    for (int nt = 0; nt < 16; ++nt) {
      short8v wb = *(const short8v*)(w2c[buf] + (nt * 16 + ln15) * 80 + gq * 16);
      ff[0][nt] = mfma32(pa8[0], wb, ff[0][nt]);
      ff[1][nt] = mfma32(pa8[1], wb, ff[1][nt]);
    }

    if (c < 31) WRITE_W2(buf ^ 1);
    __syncthreads();
  }

  #pragma unroll
  for (int ct = 0; ct < 2; ++ct)
    #pragma unroll
    for (int j = 0; j < 4; ++j) {
      int r2 = wrow0 + ct * 16 + 4 * gq + j;
      float sum = 0.f, sq = 0.f;
      float vv[16];
      #pragma unroll
      for (int nt = 0; nt < 16; ++nt) {
        int col = nt * 16 + ln15;
        float xv = bf2f(X[(size_t)r2 * 256 + col]);
        float v = ff[ct][nt][j] + b2[col] + xv;
        vv[nt] = v;
        sum += v;
        sq += v * v;
      }
      #pragma unroll
      for (int m = 1; m <= 8; m <<= 1) {
        sum += __shfl_xor(sum, m);
        sq += __shfl_xor(sq, m);
      }
      float mu = sum * (1.f / 256.f);
      float var = sq * (1.f / 256.f) - mu * mu;
      float rstd = rsqrtf(var + 1e-5f);
      #pragma unroll
      for (int nt = 0; nt < 16; ++nt) {
        int col = nt * 16 + ln15;
        out[(size_t)r2 * 256 + col] = (vv[nt] - mu) * rstd * g2[col] + be2[col];
      }
    }
  #undef STAGE_W1
  #undef LOAD_W2
  #undef WRITE_W2
}

extern "C" void kernel_launch(void* const* d_in, const int* in_sizes, int n_in,
                              void* d_out, int out_size, void* d_ws, size_t ws_size,
                              hipStream_t stream) {
  (void)in_sizes; (void)n_in; (void)out_size;
  const float* query = (const float*)d_in[0];
  const float* kv    = (const float*)d_in[1];
  const float* Wqm = (const float*)d_in[2];  const float* bq = (const float*)d_in[3];
  const float* Wkm = (const float*)d_in[4];  const float* bk = (const float*)d_in[5];
  const float* Wvm = (const float*)d_in[6];  const float* bv = (const float*)d_in[7];
  const float* Wom = (const float*)d_in[8];  const float* bo = (const float*)d_in[9];
  const float* ln1g = (const float*)d_in[10]; const float* ln1b = (const float*)d_in[11];
  const float* W1m = (const float*)d_in[12]; const float* b1 = (const float*)d_in[13];
  const float* W2m = (const float*)d_in[14]; const float* b2 = (const float*)d_in[15];
  const float* ln2g = (const float*)d_in[16]; const float* ln2b = (const float*)d_in[17];
  float* out = (float*)d_out;

  char* ws = (char*)d_ws;
  const size_t MB = 1ull << 20;
  if (ws_size < 130 * MB) return;

  // workspace layout (all bf16); Q/K/V/ctx are head-major [8][65536][32]
  u16* Vw   = (u16*)(ws);            // [0,32M)
  u16* ctxw = (u16*)(ws + 32 * MB);  // [32,64M)
  u16* Qw   = (u16*)(ws + 64 * MB);  // dead after attn
  u16* xw   = (u16*)(ws + 64 * MB);  // aliases Qw
  u16* Kw   = (u16*)(ws + 96 * MB);
  char* wb = ws + 128 * MB;
  u16* Wqt = (u16*)(wb);
  u16* Wkt = (u16*)(wb + 131072);
  u16* Wvt = (u16*)(wb + 262144);
  u16* Wot = (u16*)(wb + 393216);
  u16* W1t = (u16*)(wb + 524288);
  u16* W2t = (u16*)(wb + 1048576);

  cvt_wT<<<dim3(64, 6), 256, 0, stream>>>(Wqm, Wkm, Wvm, Wom, W1m, W2m,
                                          Wqt, Wkt, Wvt, Wot, W1t, W2t);
  gemm_q<<<dim3(512, 2), 256, 0, stream>>>(query, Wqt, bq, Qw);
  gemm_kv<<<dim3(512, 4), 256, 0, stream>>>(kv, Wkt, bk, bv, Kw, Vw);
  attn_v2<<<dim3(2048), 256, 0, stream>>>(Qw, Kw, Vw, ctxw);
  gemm_wo_ln<<<dim3(512), 256, 0, stream>>>(ctxw, Wot, bo, query, ln1g, ln1b, xw);
  ffn_v6<<<dim3(256), 512, 0, stream>>>(xw, W1t, W2t, b1, b2, ln2g, ln2b, out);
}